// Round 4
// baseline (868.865 us; speedup 1.0000x reference)
//
#include <hip/hip_runtime.h>
#include <math.h>

#define D_MODEL 1024
#define D_INNER 2048
#define D_STATE 16
#define DT_RANK 64
#define LSEQ 2048
#define NBATCH 2
#define M_TOT (NBATCH * LSEQ)   // 4096 rows total
#define DBC_STRIDE 128          // padded xproj output stride
#define CH 64                   // scan chunk length
#define NCH (LSEQ / CH)         // 32 chunks
#define KSPL 8                  // xproj K-split factor
#define OKSPL 2                 // out-proj K-split factor

typedef unsigned short ushort_t;
typedef unsigned int uint_t;
typedef __attribute__((ext_vector_type(8))) short bf16x8;
typedef __attribute__((ext_vector_type(4))) float f32x4;

__device__ __forceinline__ ushort_t f2bf_rne(float f) {
    uint_t u = __float_as_uint(f);
    u += 0x7fffu + ((u >> 16) & 1u);
    return (ushort_t)(u >> 16);
}
__device__ __forceinline__ float bf2f(ushort_t h) {
    return __uint_as_float(((uint_t)h) << 16);
}
__device__ __forceinline__ float fexp2(float x) {
#if __has_builtin(__builtin_amdgcn_exp2f)
    return __builtin_amdgcn_exp2f(x);
#else
    return exp2f(x);
#endif
}
__device__ __forceinline__ float frcp(float x) {
#if __has_builtin(__builtin_amdgcn_rcpf)
    return __builtin_amdgcn_rcpf(x);
#else
    return 1.f / x;
#endif
}
__device__ __forceinline__ float clip10(float x) {
#if __has_builtin(__builtin_amdgcn_fmed3f)
    return __builtin_amdgcn_fmed3f(x, -10.f, 10.f);
#else
    return fminf(fmaxf(x, -10.f), 10.f);
#endif
}

#define LOG2E 1.44269504f
#define NLOG2E10 -14.4269504f   // -10 * log2(e)

#define BAR()   __builtin_amdgcn_s_barrier()
#define LGKM0() asm volatile("s_waitcnt lgkmcnt(0)" ::: "memory")

#define LDFRAG_B(SRC)                                                          \
    _Pragma("unroll")                                                          \
    for (int nf = 0; nf < 4; ++nf)                                             \
        fB[nf] = *reinterpret_cast<const bf16x8*>(                             \
            &(SRC)[(bRow + nf * 16 + fm) * 32 + swz * 8]);

#define LDFRAG_A(SRC, MOFF)                                                    \
    _Pragma("unroll")                                                          \
    for (int mf = 0; mf < 4; ++mf)                                             \
        fA[mf] = *reinterpret_cast<const bf16x8*>(                             \
            &(SRC)[(aRow + (MOFF + mf) * 16 + fm) * 32 + swz * 8]);

#define MFMA_QUAD(MOFF)                                                        \
    __builtin_amdgcn_s_setprio(1);                                             \
    _Pragma("unroll")                                                          \
    for (int mf = 0; mf < 4; ++mf)                                             \
        _Pragma("unroll")                                                      \
        for (int nf = 0; nf < 4; ++nf)                                         \
            acc[MOFF + mf][nf] = __builtin_amdgcn_mfma_f32_16x16x32_bf16(      \
                fA[mf], fB[nf], acc[MOFF + mf][nf], 0, 0, 0);                  \
    __builtin_amdgcn_s_setprio(0);

// ---------------------------------------------------------------------------
// 256x256-tile 8-phase bf16 GEMM for the in-projection (M=4096,N=4096,K=1024).
// T2 (LDS swizzle) + T3/T4 (8-phase, counted vmcnt) + T5 (setprio).
// Epilogue: col<2048 -> C[row][2048] (xbuf), col>=2048 -> AUX[row][col-2048]
// (zf, row-major fp32).  Blocks are entirely in one half (n0 % 256 == 0).
// ---------------------------------------------------------------------------
#define KIN 1024
#define KTI (KIN / 64)          // 16 K-tiles

__global__ __launch_bounds__(512, 2) void gemm256_inproj(
    const ushort_t* __restrict__ Ah, const ushort_t* __restrict__ BTh,
    float* __restrict__ C, float* __restrict__ AUX)
{
    // regions (ushort units): A[bf][kh] = (bf*2+kh)*8192 ; B = 32768 + same
    __shared__ __align__(1024) ushort_t smem[65536];   // 128 KiB
    const int tid  = threadIdx.x;
    const int lane = tid & 63;
    const int w    = tid >> 6;           // wave 0..7
    const int wm   = w >> 2;             // 0..1  (M half)
    const int wn   = w & 3;              // 0..3  (N quarter)
    const int fm   = lane & 15, fk = lane >> 4;
    const int swz  = fk ^ ((fm >> 1) & 3);              // ds_read slot swizzle
    const int aRow = wm * 128;
    const int bRow = wn * 64;
    const int m0   = blockIdx.y * 256;
    const int n0   = blockIdx.x * 256;
    // staging geometry: each global_load_lds piece = 512 thr x 16B = 64 rows*2
    const int rbase = w * 16 + (lane >> 2);             // row within piece
    const int ssw   = ((lane & 3) ^ ((lane >> 3) & 3)) * 8; // src k-chunk swz

    f32x4 acc[8][4] = {};

    // stage one 256x32 k-half (16 KB) = 2 x global_load_lds dwordx4
    auto stage = [&](const ushort_t* __restrict__ g, int grow0, int kcol,
                     int regUS) {
        #pragma unroll
        for (int q = 0; q < 2; ++q) {
            const ushort_t* src =
                g + (size_t)(grow0 + q * 128 + rbase) * KIN + kcol + ssw;
            __builtin_amdgcn_global_load_lds(
                (const __attribute__((address_space(1))) void*)src,
                (__attribute__((address_space(3))) void*)(smem + regUS +
                                                          q * 4096 + w * 512),
                16, 0, 0);
        }
    };

    // prologue: tile0 kh0 (A,B), tile0 kh1 (A,B), tile1 kh0 (A,B) = 12 loads
    stage(Ah,  m0, 0,  0);
    stage(BTh, n0, 0,  32768);
    stage(Ah,  m0, 32, 8192);
    stage(BTh, n0, 32, 32768 + 8192);
    stage(Ah,  m0, 64, 16384);
    stage(BTh, n0, 64, 32768 + 16384);
    asm volatile("s_waitcnt vmcnt(8)" ::: "memory");    // tile0 kh0 resident
    BAR();

    bf16x8 fA[4], fB[4];

    for (int t = 0; t < KTI - 1; ++t) {
        const int bf = t & 1, bn = bf ^ 1;
        const ushort_t* A0 = smem + (bf * 2 + 0) * 8192;
        const ushort_t* A1 = smem + (bf * 2 + 1) * 8192;
        const ushort_t* B0 = smem + 32768 + (bf * 2 + 0) * 8192;
        const ushort_t* B1 = smem + 32768 + (bf * 2 + 1) * 8192;
        const int kc1 = (t + 1) * 64, kc2 = (t + 2) * 64;
        const bool st2 = (t + 2 < KTI);

        // phase 0: kh0, m-frags 0-3; issue A(t+1,kh1)
        LDFRAG_B(B0);
        LDFRAG_A(A0, 0);
        stage(Ah, m0, kc1 + 32, (bn * 2 + 1) * 8192);
        BAR(); LGKM0();
        MFMA_QUAD(0);
        BAR();

        // phase 1: kh0, m-frags 4-7; issue B(t+1,kh1); guard (t,kh1) for p2
        LDFRAG_A(A0, 4);
        stage(BTh, n0, kc1 + 32, 32768 + (bn * 2 + 1) * 8192);
        BAR(); LGKM0();
        MFMA_QUAD(4);
        asm volatile("s_waitcnt vmcnt(8)" ::: "memory");
        BAR();
        __builtin_amdgcn_sched_barrier(0);   // kh0 slot recycles next phase

        // phase 2: kh1, m-frags 0-3; issue A(t+2,kh0) into just-freed slot
        LDFRAG_B(B1);
        LDFRAG_A(A1, 0);
        if (st2) stage(Ah, m0, kc2, (bf * 2 + 0) * 8192);
        BAR(); LGKM0();
        MFMA_QUAD(0);
        BAR();

        // phase 3: kh1, m-frags 4-7; issue B(t+2,kh0); guard (t+1,kh0)
        LDFRAG_A(A1, 4);
        if (st2) stage(BTh, n0, kc2, 32768 + (bf * 2 + 0) * 8192);
        BAR(); LGKM0();
        MFMA_QUAD(4);
        if (t == KTI - 2) { asm volatile("s_waitcnt vmcnt(4)" ::: "memory"); }
        else              { asm volatile("s_waitcnt vmcnt(6)" ::: "memory"); }
        BAR();
        __builtin_amdgcn_sched_barrier(0);
    }

    // last tile (t = KTI-1): no staging; drain kh1 before p2
    {
        const int bf = (KTI - 1) & 1;
        const ushort_t* A0 = smem + (bf * 2 + 0) * 8192;
        const ushort_t* A1 = smem + (bf * 2 + 1) * 8192;
        const ushort_t* B0 = smem + 32768 + (bf * 2 + 0) * 8192;
        const ushort_t* B1 = smem + 32768 + (bf * 2 + 1) * 8192;

        LDFRAG_B(B0);
        LDFRAG_A(A0, 0);
        BAR(); LGKM0();
        MFMA_QUAD(0);
        BAR();

        LDFRAG_A(A0, 4);
        BAR(); LGKM0();
        MFMA_QUAD(4);
        asm volatile("s_waitcnt vmcnt(0)" ::: "memory");
        BAR();

        LDFRAG_B(B1);
        LDFRAG_A(A1, 0);
        BAR(); LGKM0();
        MFMA_QUAD(0);
        BAR();

        LDFRAG_A(A1, 4);
        BAR(); LGKM0();
        MFMA_QUAD(4);
    }

    // epilogue: both halves row-major fp32
    float* dst = (n0 < D_INNER) ? C : AUX;
    const int csub = (n0 < D_INNER) ? 0 : D_INNER;
    #pragma unroll
    for (int mf = 0; mf < 8; ++mf) {
        int row0 = m0 + aRow + mf * 16 + fk * 4;
        #pragma unroll
        for (int nf = 0; nf < 4; ++nf) {
            int col = n0 + bRow + nf * 16 + fm - csub;
            #pragma unroll
            for (int r = 0; r < 4; ++r)
                dst[(size_t)(row0 + r) * D_INNER + col] = acc[mf][nf][r];
        }
    }
}

// ---------------------------------------------------------------------------
// 256x128-tile 8-phase 2-term bf16 GEMM for the out-projection:
// P[ks] += Ah @ (Bh + Bl)^T over K-slice ks (M=4096, N=1024, K=2048, OKSPL=2).
// 512 thr = 8 waves (4M x 2N), per-wave 64x64, acc[4][4].  BK=64 as 2 k-halves.
// LDS 128 KiB: dbuf x {A[256][32]x2kh, Bh[128][32]x2kh, Bl[128][32]x2kh}.
// 4 phases/K-tile: (kh0,Bh)(kh0,Bl)(kh1,Bh)(kh1,Bl); A-frags reused across Bh/Bl.
// Staging 8 pieces/tile: p0:A_k0(2) p1:A_k1(2) p2:Bh(2) p3:Bl(2).
// vmcnt ledger (piece-sim verified): end-p0 vmcnt(3), p1 none, p2 vmcnt(6),
// p3 vmcnt(3); prologue vmcnt(3); last tile vmcnt(1)/vmcnt(0).
// ---------------------------------------------------------------------------
#define KOUT 2048
#define NTOUT 16                // K-slice 1024 / 64

__global__ __launch_bounds__(512, 2) void gemm256_outproj(
    const ushort_t* __restrict__ Ah, const ushort_t* __restrict__ BTh,
    const ushort_t* __restrict__ BTl, float* __restrict__ P)
{
    // regions (ushort units): A[bf][kh]=(bf*2+kh)*8192 (0..32768)
    // Bh[bf][kh]=32768+(bf*2+kh)*4096 ; Bl[bf][kh]=49152+(bf*2+kh)*4096
    __shared__ __align__(1024) ushort_t smem[65536];   // 128 KiB
    const int tid  = threadIdx.x;
    const int lane = tid & 63;
    const int w    = tid >> 6;
    const int wm   = w & 3;              // M quarter
    const int wn   = w >> 2;             // N half
    const int fm   = lane & 15, fk = lane >> 4;
    const int swz  = fk ^ ((fm >> 1) & 3);
    const int aRow = wm * 64;
    const int bRow = wn * 64;
    const int ks   = blockIdx.x >> 3;
    const int n0   = (blockIdx.x & 7) * 128;
    const int m0   = blockIdx.y * 256;
    const int kb   = ks * (KOUT / OKSPL);
    const int rbase = w * 16 + (lane >> 2);             // 0..127
    const int ssw   = ((lane & 3) ^ ((lane >> 3) & 3)) * 8;

    f32x4 acc[4][4] = {};

    auto stageA = [&](int t, int kh) {   // 2 pieces (256 rows x 32)
        const int kcol = kb + t * 64 + kh * 32;
        const int reg = ((t & 1) * 2 + kh) * 8192;
        #pragma unroll
        for (int q = 0; q < 2; ++q) {
            const ushort_t* src =
                Ah + (size_t)(m0 + q * 128 + rbase) * KOUT + kcol + ssw;
            __builtin_amdgcn_global_load_lds(
                (const __attribute__((address_space(1))) void*)src,
                (__attribute__((address_space(3))) void*)(smem + reg +
                                                          q * 4096 + w * 512),
                16, 0, 0);
        }
    };
    auto stageB = [&](const ushort_t* __restrict__ B, int base, int t, int kh) {
        const int kcol = kb + t * 64 + kh * 32;
        const int reg = base + ((t & 1) * 2 + kh) * 4096;
        const ushort_t* src = B + (size_t)(n0 + rbase) * KOUT + kcol + ssw;
        __builtin_amdgcn_global_load_lds(
            (const __attribute__((address_space(1))) void*)src,
            (__attribute__((address_space(3))) void*)(smem + reg + w * 512),
            16, 0, 0);
    };

    // prologue: tile0 pieces in ledger order
    stageA(0, 0);                 // O1,O2
    stageA(0, 1);                 // O3,O4
    stageB(BTh, 32768, 0, 0);     // O5
    stageB(BTh, 32768, 0, 1);     // O6
    stageB(BTl, 49152, 0, 0);     // O7
    stageB(BTl, 49152, 0, 1);     // O8
    asm volatile("s_waitcnt vmcnt(3)" ::: "memory");    // O1..O5 resident
    BAR();

    bf16x8 fA[4], fB[4];

    for (int t = 0; t < NTOUT - 1; ++t) {
        const int bf = t & 1;
        const ushort_t* A0  = smem + (bf * 2 + 0) * 8192;
        const ushort_t* A1  = smem + (bf * 2 + 1) * 8192;
        const ushort_t* Bh0 = smem + 32768 + (bf * 2 + 0) * 4096;
        const ushort_t* Bh1 = smem + 32768 + (bf * 2 + 1) * 4096;
        const ushort_t* Bl0 = smem + 49152 + (bf * 2 + 0) * 4096;
        const ushort_t* Bl1 = smem + 49152 + (bf * 2 + 1) * 4096;

        // p0: kh0 x Bh; issue A(t+1) kh0
        LDFRAG_B(Bh0);
        LDFRAG_A(A0, 0);
        stageA(t + 1, 0);
        BAR(); LGKM0();
        MFMA_QUAD(0);
        asm volatile("s_waitcnt vmcnt(3)" ::: "memory");
        BAR();
        __builtin_amdgcn_sched_barrier(0);

        // p1: kh0 x Bl (A-frags reused); issue A(t+1) kh1
        LDFRAG_B(Bl0);
        stageA(t + 1, 1);
        BAR(); LGKM0();
        MFMA_QUAD(0);
        BAR();

        // p2: kh1 x Bh; issue Bh(t+1) both kh
        LDFRAG_B(Bh1);
        LDFRAG_A(A1, 0);
        stageB(BTh, 32768, t + 1, 0);
        stageB(BTh, 32768, t + 1, 1);
        BAR(); LGKM0();
        MFMA_QUAD(0);
        asm volatile("s_waitcnt vmcnt(6)" ::: "memory");
        BAR();
        __builtin_amdgcn_sched_barrier(0);

        // p3: kh1 x Bl; issue Bl(t+1) both kh
        LDFRAG_B(Bl1);
        stageB(BTl, 49152, t + 1, 0);
        stageB(BTl, 49152, t + 1, 1);
        BAR(); LGKM0();
        MFMA_QUAD(0);
        asm volatile("s_waitcnt vmcnt(3)" ::: "memory");
        BAR();
        __builtin_amdgcn_sched_barrier(0);
    }

    // last tile (no staging); entry outstanding: Bh_k1, Bl_k0, Bl_k1
    {
        const int bf = (NTOUT - 1) & 1;
        const ushort_t* A0  = smem + (bf * 2 + 0) * 8192;
        const ushort_t* A1  = smem + (bf * 2 + 1) * 8192;
        const ushort_t* Bh0 = smem + 32768 + (bf * 2 + 0) * 4096;
        const ushort_t* Bh1 = smem + 32768 + (bf * 2 + 1) * 4096;
        const ushort_t* Bl0 = smem + 49152 + (bf * 2 + 0) * 4096;
        const ushort_t* Bl1 = smem + 49152 + (bf * 2 + 1) * 4096;

        LDFRAG_B(Bh0);
        LDFRAG_A(A0, 0);
        BAR(); LGKM0();
        MFMA_QUAD(0);
        asm volatile("s_waitcnt vmcnt(1)" ::: "memory");
        BAR();

        LDFRAG_B(Bl0);
        BAR(); LGKM0();
        MFMA_QUAD(0);
        BAR();

        LDFRAG_B(Bh1);
        LDFRAG_A(A1, 0);
        BAR(); LGKM0();
        MFMA_QUAD(0);
        asm volatile("s_waitcnt vmcnt(0)" ::: "memory");
        BAR();

        LDFRAG_B(Bl1);
        BAR(); LGKM0();
        MFMA_QUAD(0);
    }

    // epilogue: partial P[ks][m][n] row-major
    float* Pq = P + (size_t)ks * M_TOT * D_MODEL;
    #pragma unroll
    for (int mf = 0; mf < 4; ++mf) {
        int row0 = m0 + aRow + mf * 16 + fk * 4;
        #pragma unroll
        for (int nf = 0; nf < 4; ++nf) {
            int col = n0 + bRow + nf * 16 + fm;
            #pragma unroll
            for (int r = 0; r < 4; ++r)
                Pq[(size_t)(row0 + r) * D_MODEL + col] = acc[mf][nf][r];
        }
    }
}

// ---------------------------------------------------------------------------
// Split-bf16 MFMA GEMM, BT[N][K] pre-transposed, 128x128 tile, 4 waves, BK=32.
// TERMS: 1 = AhBh; 2 = AhBh + AhBl; 3 = AhBh + AlBh + AhBl.
// MODE 0: plain C[M][N].
// MODE 3: xproj K-split (KSPL): blockIdx.x = k-slice, n0 = 0, partial -> C + ks*M*N.
// MODE 5: dtproj: epilogue adds bias (AUX) + softplus, row-major C[m][d].
// ---------------------------------------------------------------------------
template <int MODE, int TERMS>
__global__ __launch_bounds__(256) void gemm_bf16s(
    const ushort_t* __restrict__ Ah, const ushort_t* __restrict__ Al,
    const ushort_t* __restrict__ BTh, const ushort_t* __restrict__ BTl,
    float* __restrict__ C, float* __restrict__ AUX, int M, int N, int K)
{
    __shared__ __align__(16) ushort_t smem[4 * 128 * 32];   // Ah|Al|Bh|Bl tiles
    ushort_t* sAh = smem;
    ushort_t* sAl = smem + 4096;
    ushort_t* sBh = smem + 8192;
    ushort_t* sBl = smem + 12288;
    const int tid = threadIdx.x;
    const int lane = tid & 63;
    const int m0 = blockIdx.y * 128;
    int ks = 0, nblk = blockIdx.x;
    if (MODE == 3) { ks = blockIdx.x; nblk = 0; }
    const int n0 = nblk * 128;
    const int wave = tid >> 6;
    const int mw = (wave & 1) * 64, nw = (wave >> 1) * 64;
    const int fm = lane & 15, fk = lane >> 4;
    const int swz = fk ^ ((fm >> 1) & 3);

    f32x4 acc[4][4] = {};

    const int r_st0 = tid >> 2, cp0 = tid & 3;
    const int r_st1 = (256 + tid) >> 2, cp1 = tid & 3;
    const int cl0 = cp0 ^ ((r_st0 >> 1) & 3);
    const int cl1 = cp1 ^ ((r_st1 >> 1) & 3);
    const int ldsb0 = (tid & ~63) * 16;
    const int ldsb1 = (256 + (tid & ~63)) * 16;

    const int kbeg = (MODE == 3) ? ks * (K / KSPL) : 0;
    const int kend = (MODE == 3) ? kbeg + K / KSPL : K;

    for (int k0 = kbeg; k0 < kend; k0 += 32) {
        __syncthreads();
        {
            size_t ga0 = (size_t)(m0 + r_st0) * K + k0 + cl0 * 8;
            size_t ga1 = (size_t)(m0 + r_st1) * K + k0 + cl1 * 8;
            size_t gb0 = (size_t)(n0 + r_st0) * K + k0 + cl0 * 8;
            size_t gb1 = (size_t)(n0 + r_st1) * K + k0 + cl1 * 8;
            __builtin_amdgcn_global_load_lds(
                (const __attribute__((address_space(1))) void*)(Ah + ga0),
                (__attribute__((address_space(3))) void*)((char*)sAh + ldsb0), 16, 0, 0);
            __builtin_amdgcn_global_load_lds(
                (const __attribute__((address_space(1))) void*)(Ah + ga1),
                (__attribute__((address_space(3))) void*)((char*)sAh + ldsb1), 16, 0, 0);
            if (TERMS >= 3) {
                __builtin_amdgcn_global_load_lds(
                    (const __attribute__((address_space(1))) void*)(Al + ga0),
                    (__attribute__((address_space(3))) void*)((char*)sAl + ldsb0), 16, 0, 0);
                __builtin_amdgcn_global_load_lds(
                    (const __attribute__((address_space(1))) void*)(Al + ga1),
                    (__attribute__((address_space(3))) void*)((char*)sAl + ldsb1), 16, 0, 0);
            }
            __builtin_amdgcn_global_load_lds(
                (const __attribute__((address_space(1))) void*)(BTh + gb0),
                (__attribute__((address_space(3))) void*)((char*)sBh + ldsb0), 16, 0, 0);
            __builtin_amdgcn_global_load_lds(
                (const __attribute__((address_space(1))) void*)(BTh + gb1),
                (__attribute__((address_space(3))) void*)((char*)sBh + ldsb1), 16, 0, 0);
            if (TERMS >= 2) {
                __builtin_amdgcn_global_load_lds(
                    (const __attribute__((address_space(1))) void*)(BTl + gb0),
                    (__attribute__((address_space(3))) void*)((char*)sBl + ldsb0), 16, 0, 0);
                __builtin_amdgcn_global_load_lds(
                    (const __attribute__((address_space(1))) void*)(BTl + gb1),
                    (__attribute__((address_space(3))) void*)((char*)sBl + ldsb1), 16, 0, 0);
            }
        }
        __syncthreads();

        bf16x8 fAh[4], fAl[4], fBh[4], fBl[4];
        #pragma unroll
        for (int t = 0; t < 4; ++t) {
            int ra = (mw + t * 16 + fm) * 32 + swz * 8;
            int rb = (nw + t * 16 + fm) * 32 + swz * 8;
            fAh[t] = *reinterpret_cast<const bf16x8*>(&sAh[ra]);
            if (TERMS >= 3) fAl[t] = *reinterpret_cast<const bf16x8*>(&sAl[ra]);
            fBh[t] = *reinterpret_cast<const bf16x8*>(&sBh[rb]);
            if (TERMS >= 2) fBl[t] = *reinterpret_cast<const bf16x8*>(&sBl[rb]);
        }
        #pragma unroll
        for (int i = 0; i < 4; ++i)
            #pragma unroll
            for (int j = 0; j < 4; ++j) {
                acc[i][j] = __builtin_amdgcn_mfma_f32_16x16x32_bf16(fAh[i], fBh[j], acc[i][j], 0, 0, 0);
                if (TERMS >= 3)
                    acc[i][j] = __builtin_amdgcn_mfma_f32_16x16x32_bf16(fAl[i], fBh[j], acc[i][j], 0, 0, 0);
                if (TERMS >= 2)
                    acc[i][j] = __builtin_amdgcn_mfma_f32_16x16x32_bf16(fAh[i], fBl[j], acc[i][j], 0, 0, 0);
            }
    }

    float* Cq = (MODE == 3) ? C + (size_t)ks * M * N : C;
    #pragma unroll
    for (int i = 0; i < 4; ++i) {
        int row0 = m0 + mw + i * 16 + fk * 4;
        #pragma unroll
        for (int j = 0; j < 4; ++j) {
            int col = n0 + nw + j * 16 + fm;
            if (MODE == 5) {
                const float* bias = (const float*)AUX;
                float bc_ = bias[col];
                #pragma unroll
                for (int r = 0; r < 4; ++r) {
                    float t = acc[i][j][r] + bc_;
                    C[(size_t)(row0 + r) * N + col] =
                        fmaxf(t, 0.f) + log1pf(__expf(-fabsf(t)));
                }
            } else {
                #pragma unroll
                for (int r = 0; r < 4; ++r)
                    Cq[(size_t)(row0 + r) * N + col] = acc[i][j][r];
            }
        }
    }
}

// ---------------------------------------------------------------------------
// xproj split-K reduce: dbc = sum_ks dbcp[ks] (fp32 [m][128], cols 64..96 are
// B|C consumed by the scan); dbch[m][c] bf16 for c in [0,64) (dtproj A).
// ---------------------------------------------------------------------------
__global__ __launch_bounds__(256) void xproj_red_k(
    const float* __restrict__ dbcp, float* __restrict__ dbc,
    ushort_t* __restrict__ dbch)
{
    int g = blockIdx.x * 256 + threadIdx.x;      // over 4096*128
    int m = g >> 7, c = g & 127;
    float s = 0.f;
    #pragma unroll
    for (int ks = 0; ks < KSPL; ++ks)
        s += dbcp[(size_t)ks * M_TOT * DBC_STRIDE + g];
    dbc[g] = s;
    if (c < 64)
        dbch[(size_t)m * 64 + c] = f2bf_rne(s);
}

// ---------------------------------------------------------------------------
// out-proj split-K reduce: out = p0 + p1 (float4).
// ---------------------------------------------------------------------------
__global__ __launch_bounds__(256) void outred_k(
    const float* __restrict__ p, float* __restrict__ out)
{
    int i4 = (blockIdx.x * 256 + threadIdx.x) * 4;
    f32x4 a = *reinterpret_cast<const f32x4*>(p + i4);
    f32x4 b = *reinterpret_cast<const f32x4*>(p + (size_t)M_TOT * D_MODEL + i4);
    *reinterpret_cast<f32x4*>(out + i4) = a + b;
}

// ---------------------------------------------------------------------------
// x -> xh bf16 (hi only), elementwise.
// ---------------------------------------------------------------------------
__global__ __launch_bounds__(256) void cast_h_k(
    const float* __restrict__ X, ushort_t* __restrict__ Xh)
{
    int i4 = (blockIdx.x * 256 + threadIdx.x) * 4;
    float4 v = *reinterpret_cast<const float4*>(X + i4);
    ushort2 a = make_ushort2(f2bf_rne(v.x), f2bf_rne(v.y));
    ushort2 b = make_ushort2(f2bf_rne(v.z), f2bf_rne(v.w));
    *reinterpret_cast<ushort2*>(Xh + i4)     = a;
    *reinterpret_cast<ushort2*>(Xh + i4 + 2) = b;
}

// ---------------------------------------------------------------------------
// W[K][N] fp32 -> WT[N][K] bf16 hi/lo (tiled transpose, exact dims).
// ---------------------------------------------------------------------------
__global__ __launch_bounds__(256) void transpose_cast_k(
    const float* __restrict__ W, ushort_t* __restrict__ Th, ushort_t* __restrict__ Tl,
    int K, int N)
{
    __shared__ float tile[32][33];
    int n0 = blockIdx.x * 32, k0 = blockIdx.y * 32;
    int tx = threadIdx.x & 31, ty = threadIdx.x >> 5;
    #pragma unroll
    for (int i = 0; i < 32; i += 8)
        tile[ty + i][tx] = W[(size_t)(k0 + ty + i) * N + n0 + tx];
    __syncthreads();
    #pragma unroll
    for (int i = 0; i < 32; i += 8) {
        float v = tile[tx][ty + i];
        ushort_t h = f2bf_rne(v);
        ushort_t l = f2bf_rne(v - bf2f(h));
        size_t o = (size_t)(n0 + ty + i) * K + k0 + tx;
        Th[o] = h; Tl[o] = l;
    }
}

// ---------------------------------------------------------------------------
// W[K][N] fp32 -> WT[Npad][K] bf16 hi only, zero-padded rows N..Npad.
// ---------------------------------------------------------------------------
__global__ __launch_bounds__(256) void transpose_cast_pad_k(
    const float* __restrict__ W, ushort_t* __restrict__ Th, int K, int N)
{
    __shared__ float tile[32][33];
    int n0 = blockIdx.x * 32, k0 = blockIdx.y * 32;
    int tx = threadIdx.x & 31, ty = threadIdx.x >> 5;
    #pragma unroll
    for (int i = 0; i < 32; i += 8)
        tile[ty + i][tx] = (n0 + tx < N) ? W[(size_t)(k0 + ty + i) * N + n0 + tx] : 0.f;
    __syncthreads();
    #pragma unroll
    for (int i = 0; i < 32; i += 8) {
        float v = tile[tx][ty + i];
        size_t o = (size_t)(n0 + ty + i) * K + k0 + tx;
        Th[o] = f2bf_rne(v);
    }
}

// ---------------------------------------------------------------------------
// Depthwise causal conv + bias + SiLU. Reads compact xbuf[m][2048].
// Outputs xinh [m][d] bf16 (xproj A, 1-term) and xf [m][d] fp32 (scan).
// ---------------------------------------------------------------------------
__global__ __launch_bounds__(256) void conv_silu_k(
    const float* __restrict__ xbuf, const float* __restrict__ Wc,
    const float* __restrict__ bc, ushort_t* __restrict__ xinh,
    float* __restrict__ xf)
{
    __shared__ float tile[67][64];
    const int c0 = blockIdx.x * 64;
    const int m0 = blockIdx.y * 64;
    const int bstart = m0 & ~(LSEQ - 1);
    const int tid = threadIdx.x;

    for (int e = tid; e < 67 * 64; e += 256) {
        int r = e >> 6, c = e & 63;
        int g = m0 - 3 + r;
        tile[r][c] = (g >= bstart) ? xbuf[(size_t)g * D_INNER + c0 + c] : 0.f;
    }
    __syncthreads();

    const int c_l = tid & 63, mg = tid >> 6;
    const int c = c0 + c_l;
    const float w0 = Wc[c], w1 = Wc[D_INNER + c];
    const float w2 = Wc[2 * D_INNER + c], w3 = Wc[3 * D_INNER + c];
    const float bb = bc[c];
    #pragma unroll
    for (int mi = 0; mi < 16; ++mi) {
        int r = mg * 16 + mi;
        float acc = bb + tile[r][c_l] * w0 + tile[r + 1][c_l] * w1
                       + tile[r + 2][c_l] * w2 + tile[r + 3][c_l] * w3;
        float sv = acc / (1.f + __expf(-acc));
        xinh[(size_t)(m0 + r) * D_INNER + c] = f2bf_rne(sv);
        xf[(size_t)(m0 + r) * D_INNER + c] = sv;
    }
}

// ---------------------------------------------------------------------------
// Chunked selective scan, register-pipelined version (no LDS, no barriers).
// One thread per channel d; 16 states in VGPRs; dt/x/z loaded coalesced into
// named register double-buffers (8-row groups, prefetched one group ahead);
// B/C rows are block-uniform -> compiler lowers to scalar loads (L2-resident).
// A-exponent in log2 domain.  Pass 1: chunk summaries asum (log2), s_end.
// ---------------------------------------------------------------------------
#define SCAN_LOAD2(DBUF, XBUF, G)                                              \
    _Pragma("unroll")                                                          \
    for (int j = 0; j < 8; ++j) {                                              \
        const size_t rr = (mbase + (G) * 8 + j) * D_INNER + d;                 \
        DBUF[j] = dtf[rr]; XBUF[j] = xf[rr];                                   \
    }

#define SCAN_LOAD3(DBUF, XBUF, ZBUF, G)                                        \
    _Pragma("unroll")                                                          \
    for (int j = 0; j < 8; ++j) {                                              \
        const size_t rr = (mbase + (G) * 8 + j) * D_INNER + d;                 \
        DBUF[j] = dtf[rr]; XBUF[j] = xf[rr]; ZBUF[j] = zf[rr];                 \
    }

__global__ __launch_bounds__(256) void scan_sum_k3(
    const float* __restrict__ dtf, const float* __restrict__ xf,
    const float* __restrict__ dbc, const float* __restrict__ A_log,
    float* __restrict__ asumb, float* __restrict__ sendb)
{
    const int tid = threadIdx.x;
    const int c0 = blockIdx.x << 8;
    const int ck = blockIdx.y;
    const int b  = blockIdx.z;
    const size_t mbase = (size_t)b * LSEQ + (size_t)ck * CH;
    const int d = c0 + tid;

    float AdnL2[16];
    #pragma unroll
    for (int n = 0; n < 16; ++n)
        AdnL2[n] = -__expf(A_log[d * D_STATE + n]) * LOG2E;

    float s[16] = {};
    float asum[16] = {};
    float dA[8], xA[8], dB[8], xB[8];

    #define SCAN_SUM_G(DBUF, XBUF, G)                                          \
        _Pragma("unroll")                                                      \
        for (int j = 0; j < 8; ++j) {                                          \
            const int t = (G) * 8 + j;                                         \
            const float* bc = dbc + (mbase + t) * DBC_STRIDE + 64;             \
            const float dv = DBUF[j], xv = XBUF[j];                            \
            const float p = dv * xv;                                           \
            _Pragma("unroll")                                                  \
            for (int n = 0; n < 16; ++n) {                                     \
                float a = fmaxf(dv * AdnL2[n], NLOG2E10);                      \
                asum[n] += a;                                                  \
                float e = fexp2(a);                                            \
                s[n] = clip10(fmaf(s[n], e, p * bc[n]));                       \
            }                                                                  \
        }

    SCAN_LOAD2(dA, xA, 0);
    SCAN_LOAD2(dB, xB, 1);
    #pragma unroll
    for (int g = 0; g < 8; g += 2) {
        SCAN_SUM_G(dA, xA, g);
        if (g + 2 < 8) SCAN_LOAD2(dA, xA, g + 2);
        SCAN_SUM_G(dB, xB, g + 1);
        if (g + 3 < 8) SCAN_LOAD2(dB, xB, g + 3);
    }
    #undef SCAN_SUM_G

    #pragma unroll
    for (int n = 0; n < 16; ++n) {
        size_t o = (((size_t)(b * NCH + ck) * 16) + n) * D_INNER + d;
        asumb[o] = asum[n];
        sendb[o] = s[n];
    }
}

// ---------------------------------------------------------------------------
// Pass 2: sequential combine over chunk summaries -> entry state per chunk.
// Layout [b][ck][n][d] for coalescing; asum is in log2 domain.
// ---------------------------------------------------------------------------
__global__ __launch_bounds__(256) void scan_fix_k2(
    const float* __restrict__ asumb, const float* __restrict__ sendb,
    float* __restrict__ sinb)
{
    int g = blockIdx.x * 256 + threadIdx.x;     // d + 2048*(n + 16*b)
    int d = g & (D_INNER - 1);
    int n = (g >> 11) & 15;
    int b = g >> 15;
    float s = 0.f;
    for (int ck = 0; ck < NCH; ++ck) {
        size_t idx = (((size_t)(b * NCH + ck) * 16) + n) * D_INNER + d;
        sinb[idx] = s;
        s = clip10(fmaf(s, fexp2(asumb[idx]), sendb[idx]));
    }
}

// ---------------------------------------------------------------------------
// Pass 3: recompute local scan from entry state, n-sum in registers (4-way
// partials), gate, store y bf16 [m][d].  Same pipelined structure as pass 1.
// ---------------------------------------------------------------------------
__global__ __launch_bounds__(256) void scan_apply_k3(
    const float* __restrict__ dtf, const float* __restrict__ xf,
    const float* __restrict__ dbc, const float* __restrict__ zf,
    const float* __restrict__ sinb, const float* __restrict__ A_log,
    const float* __restrict__ Dv, ushort_t* __restrict__ Yh)
{
    const int tid = threadIdx.x;
    const int c0 = blockIdx.x << 8;
    const int ck = blockIdx.y;
    const int b  = blockIdx.z;
    const size_t mbase = (size_t)b * LSEQ + (size_t)ck * CH;
    const int d = c0 + tid;

    float AdnL2[16];
    #pragma unroll
    for (int n = 0; n < 16; ++n)
        AdnL2[n] = -__expf(A_log[d * D_STATE + n]) * LOG2E;
    const float Dd = Dv[d];

    float s[16];
    #pragma unroll
    for (int n = 0; n < 16; ++n)
        s[n] = sinb[(((size_t)(b * NCH + ck) * 16) + n) * D_INNER + d];

    float dA[8], xA[8], zA[8], dB[8], xB[8], zB[8];

    #define SCAN_APPLY_G(DBUF, XBUF, ZBUF, G)                                  \
        _Pragma("unroll")                                                      \
        for (int j = 0; j < 8; ++j) {                                          \
            const int t = (G) * 8 + j;                                         \
            const float* bc = dbc + (mbase + t) * DBC_STRIDE + 64;             \
            const float dv = DBUF[j], xv = XBUF[j];                            \
            const float p = dv * xv;                                           \
            float y0 = Dd * xv, y1 = 0.f, y2 = 0.f, y3 = 0.f;                  \
            _Pragma("unroll")                                                  \
            for (int n = 0; n < 16; n += 4) {                                  \
                float a0 = fmaxf(dv * AdnL2[n + 0], NLOG2E10);                 \
                float a1 = fmaxf(dv * AdnL2[n + 1], NLOG2E10);                 \
                float a2 = fmaxf(dv * AdnL2[n + 2], NLOG2E10);                 \
                float a3 = fmaxf(dv * AdnL2[n + 3], NLOG2E10);                 \
                s[n + 0] = clip10(fmaf(s[n + 0], fexp2(a0), p * bc[n + 0]));   \
                s[n + 1] = clip10(fmaf(s[n + 1], fexp2(a1), p * bc[n + 1]));   \
                s[n + 2] = clip10(fmaf(s[n + 2], fexp2(a2), p * bc[n + 2]));   \
                s[n + 3] = clip10(fmaf(s[n + 3], fexp2(a3), p * bc[n + 3]));   \
                y0 = fmaf(s[n + 0], bc[16 + n + 0], y0);                       \
                y1 = fmaf(s[n + 1], bc[16 + n + 1], y1);                       \
                y2 = fmaf(s[n + 2], bc[16 + n + 2], y2);                       \
                y3 = fmaf(s[n + 3], bc[16 + n + 3], y3);                       \
            }                                                                  \
            const float y = (y0 + y1) + (y2 + y3);                             \
            const float zz = ZBUF[j];                                          \
            const float gate = zz * frcp(1.f + fexp2(zz * -LOG2E));            \
            Yh[(mbase + t) * D_INNER + d] = f2bf_rne(y * gate);                \
        }

    SCAN_LOAD3(dA, xA, zA, 0);
    SCAN_LOAD3(dB, xB, zB, 1);
    #pragma unroll
    for (int g = 0; g < 8; g += 2) {
        SCAN_APPLY_G(dA, xA, zA, g);
        if (g + 2 < 8) SCAN_LOAD3(dA, xA, zA, g + 2);
        SCAN_APPLY_G(dB, xB, zB, g + 1);
        if (g + 3 < 8) SCAN_LOAD3(dB, xB, zB, g + 3);
    }
    #undef SCAN_APPLY_G
}

// ---------------------------------------------------------------------------
extern "C" void kernel_launch(void* const* d_in, const int* in_sizes, int n_in,
                              void* d_out, int out_size, void* d_ws, size_t ws_size,
                              hipStream_t stream)
{
    const float* x       = (const float*)d_in[0];
    const float* W_in    = (const float*)d_in[1];
    const float* W_conv  = (const float*)d_in[2];
    const float* b_conv  = (const float*)d_in[3];
    const float* W_xproj = (const float*)d_in[4];
    const float* W_dt    = (const float*)d_in[5];
    const float* b_dt    = (const float*)d_in[6];
    const float* A_log   = (const float*)d_in[7];
    const float* Dv      = (const float*)d_in[8];
    const float* W_out   = (const float*)d_in[9];
    float* out = (float*)d_out;

    // fp32 region
    float* xbuf = (float*)d_ws;                              // [4096][2048]
    float* zf   = xbuf + (size_t)M_TOT * D_INNER;            // [4096][2048] z row-major
    float* dbc  = zf + (size_t)M_TOT * D_INNER;              // [4096][128]
    float* BCT  = dbc + (size_t)M_TOT * DBC_STRIDE;          // [32][4096] (unused slot)
    // bf16 region (layout slots; several aliased below)
    ushort_t* xh     = (ushort_t*)(BCT + (size_t)32 * M_TOT);
    ushort_t* xl     = xh + (size_t)M_TOT * D_MODEL;          // (slot)
    ushort_t* WinTh  = xl + (size_t)M_TOT * D_MODEL;          // [4096][1024]
    ushort_t* WinTl  = WinTh + (size_t)2 * D_INNER * D_MODEL; // (slot)
    ushort_t* WoutTh = WinTl + (size_t)2 * D_INNER * D_MODEL; // [1024][2048]
    ushort_t* WoutTl = WoutTh + (size_t)D_MODEL * D_INNER;
    ushort_t* WxTh   = WoutTl + (size_t)D_MODEL * D_INNER;    // [128][2048]
    ushort_t* WxTl   = WxTh + (size_t)DBC_STRIDE * D_INNER;   // (slot)
    ushort_t* xinh   = WxTl + (size_t)DBC_STRIDE * D_INNER;   // [4096][2048]
    ushort_t* xinl   = xinh + (size_t)M_TOT * D_INNER;        // (slot)
    ushort_t* yh     = xinl + (size_t)M_TOT * D_INNER;        // [4096][2048]
    ushort_t* yl     = yh + (size_t)M_TOT * D_INNER;          // (slot)
    ushort_t* WdtTh  = yl + (size_t)M_TOT * D_INNER;          // [2048][64]
    ushort_t* dbch   = WdtTh + (size_t)D_INNER * DT_RANK;     // [4096][64]
    // aliases (stream-ordered reuse of dead regions):
    float* xf   = (float*)xh;    // [4096][2048] over xh|xl|WinTh|WinTl (dead after gemm#1)
    float* dtf  = (float*)xinh;  // [4096][2048] over xinh|xinl (dead after xproj gemm)
    float* dbcp = (float*)yh;    // [8][4096][128] over yh|yl (dead until scan_apply)
    float* pout = (float*)xh;    // [2][4096][1024] over xf region (dead after scan)
    const size_t NSUM = (size_t)NBATCH * NCH * D_INNER * D_STATE;
    float* asumb = xbuf;         // over xbuf (dead after conv)
    float* sendb = xbuf + NSUM;
    float* sinb  = xbuf + 2 * NSUM;

    // precompute: casts + weight transposes
    cast_h_k<<<(M_TOT * D_MODEL) / 1024, 256, 0, stream>>>(x, xh);
    transpose_cast_pad_k<<<dim3((2 * D_INNER) / 32, D_MODEL / 32), 256, 0, stream>>>(
        W_in, WinTh, D_MODEL, 2 * D_INNER);
    transpose_cast_k<<<dim3(D_MODEL / 32, D_INNER / 32), 256, 0, stream>>>(
        W_out, WoutTh, WoutTl, D_INNER, D_MODEL);
    transpose_cast_pad_k<<<dim3(DBC_STRIDE / 32, D_INNER / 32), 256, 0, stream>>>(
        W_xproj, WxTh, D_INNER, DT_RANK + 2 * D_STATE);
    transpose_cast_pad_k<<<dim3(D_INNER / 32, DT_RANK / 32), 256, 0, stream>>>(
        W_dt, WdtTh, DT_RANK, D_INNER);

    // 1) in-proj (256x256 8-phase): x-half -> xbuf, z-half -> zf[m][d]
    gemm256_inproj<<<dim3(16, 16), 512, 0, stream>>>(xh, WinTh, xbuf, zf);
    // 2) conv + silu -> xinh [m][d] bf16 + xf [m][d] fp32
    conv_silu_k<<<dim3(D_INNER / 64, M_TOT / 64), 256, 0, stream>>>(
        xbuf, W_conv, b_conv, xinh, xf);
    // 3) xproj (1-term, K-split x8) -> dbcp partials -> dbc + dbch bf16
    gemm_bf16s<3, 1><<<dim3(KSPL, 32), 256, 0, stream>>>(
        xinh, nullptr, WxTh, nullptr, dbcp, nullptr, M_TOT, DBC_STRIDE, D_INNER);
    xproj_red_k<<<(M_TOT * DBC_STRIDE) / 256, 256, 0, stream>>>(dbcp, dbc, dbch);
    // 4) dtproj via MFMA (MODE 5): dtf[m][d] = softplus(dbch @ WdtT + b_dt)
    gemm_bf16s<5, 1><<<dim3(D_INNER / 128, M_TOT / 128), 256, 0, stream>>>(
        dbch, nullptr, WdtTh, nullptr, dtf, (float*)b_dt, M_TOT, D_INNER, DT_RANK);
    // 5) chunked scan (register-pipelined): summaries -> combine -> apply+gate
    scan_sum_k3<<<dim3(D_INNER / 256, NCH, NBATCH), 256, 0, stream>>>(
        dtf, xf, dbc, A_log, asumb, sendb);
    scan_fix_k2<<<(NBATCH * D_STATE * D_INNER) / 256, 256, 0, stream>>>(
        asumb, sendb, sinb);
    scan_apply_k3<<<dim3(D_INNER / 256, NCH, NBATCH), 256, 0, stream>>>(
        dtf, xf, dbc, zf, sinb, A_log, Dv, yh);
    // 6) out-proj (256x128 8-phase 2-term, K-split x2) -> pout partials -> out
    gemm256_outproj<<<dim3(16, 16), 512, 0, stream>>>(yh, WoutTh, WoutTl, pout);
    outred_k<<<(M_TOT * D_MODEL) / 1024, 256, 0, stream>>>(pout, out);
}

// Round 5
// 335.412 us; speedup vs baseline: 2.5904x; 2.5904x over previous
//
#include <hip/hip_runtime.h>
#include <math.h>

#define D_MODEL 1024
#define D_INNER 2048
#define D_STATE 16
#define DT_RANK 64
#define LSEQ 2048
#define NBATCH 2
#define M_TOT (NBATCH * LSEQ)   // 4096 rows total
#define DBC_STRIDE 128          // padded xproj output stride
#define CH 64                   // scan chunk length
#define NCH (LSEQ / CH)         // 32 chunks
#define KSPL 8                  // xproj K-split factor
#define OKSPL 2                 // out-proj K-split factor

typedef unsigned short ushort_t;
typedef unsigned int uint_t;
typedef __attribute__((ext_vector_type(8))) short bf16x8;
typedef __attribute__((ext_vector_type(4))) float f32x4;

__device__ __forceinline__ ushort_t f2bf_rne(float f) {
    uint_t u = __float_as_uint(f);
    u += 0x7fffu + ((u >> 16) & 1u);
    return (ushort_t)(u >> 16);
}
__device__ __forceinline__ float bf2f(ushort_t h) {
    return __uint_as_float(((uint_t)h) << 16);
}
__device__ __forceinline__ float fexp2(float x) {
#if __has_builtin(__builtin_amdgcn_exp2f)
    return __builtin_amdgcn_exp2f(x);
#else
    return exp2f(x);
#endif
}
__device__ __forceinline__ float frcp(float x) {
#if __has_builtin(__builtin_amdgcn_rcpf)
    return __builtin_amdgcn_rcpf(x);
#else
    return 1.f / x;
#endif
}
__device__ __forceinline__ float clip10(float x) {
#if __has_builtin(__builtin_amdgcn_fmed3f)
    return __builtin_amdgcn_fmed3f(x, -10.f, 10.f);
#else
    return fminf(fmaxf(x, -10.f), 10.f);
#endif
}

#define LOG2E 1.44269504f
#define NLOG2E10 -14.4269504f   // -10 * log2(e)

#define BAR()   __builtin_amdgcn_s_barrier()
#define LGKM0() asm volatile("s_waitcnt lgkmcnt(0)" ::: "memory")
#define GLDS(SRC, DST)                                                         \
    __builtin_amdgcn_global_load_lds(                                          \
        (const __attribute__((address_space(1))) void*)(SRC),                  \
        (__attribute__((address_space(3))) void*)(DST), 16, 0, 0)

#define LDFRAG_B(SRC)                                                          \
    _Pragma("unroll")                                                          \
    for (int nf = 0; nf < 4; ++nf)                                             \
        fB[nf] = *reinterpret_cast<const bf16x8*>(                             \
            &(SRC)[(bRow + nf * 16 + fm) * 32 + swz * 8]);

#define LDFRAG_A(SRC, MOFF)                                                    \
    _Pragma("unroll")                                                          \
    for (int mf = 0; mf < 4; ++mf)                                             \
        fA[mf] = *reinterpret_cast<const bf16x8*>(                             \
            &(SRC)[(aRow + (MOFF + mf) * 16 + fm) * 32 + swz * 8]);

#define MFMA_QUAD(MOFF)                                                        \
    __builtin_amdgcn_s_setprio(1);                                             \
    _Pragma("unroll")                                                          \
    for (int mf = 0; mf < 4; ++mf)                                             \
        _Pragma("unroll")                                                      \
        for (int nf = 0; nf < 4; ++nf)                                         \
            acc[MOFF + mf][nf] = __builtin_amdgcn_mfma_f32_16x16x32_bf16(      \
                fA[mf], fB[nf], acc[MOFF + mf][nf], 0, 0, 0);                  \
    __builtin_amdgcn_s_setprio(0);

// ---------------------------------------------------------------------------
// 256x256-tile 8-phase bf16 GEMM for the in-projection (M=4096,N=4096,K=1024).
// ---------------------------------------------------------------------------
#define KIN 1024
#define KTI (KIN / 64)          // 16 K-tiles

__global__ __launch_bounds__(512, 2) void gemm256_inproj(
    const ushort_t* __restrict__ Ah, const ushort_t* __restrict__ BTh,
    float* __restrict__ C, float* __restrict__ AUX)
{
    // regions (ushort units): A[bf][kh] = (bf*2+kh)*8192 ; B = 32768 + same
    __shared__ __align__(1024) ushort_t smem[65536];   // 128 KiB
    const int tid  = threadIdx.x;
    const int lane = tid & 63;
    const int w    = tid >> 6;           // wave 0..7
    const int wm   = w >> 2;             // 0..1  (M half)
    const int wn   = w & 3;              // 0..3  (N quarter)
    const int fm   = lane & 15, fk = lane >> 4;
    const int swz  = fk ^ ((fm >> 1) & 3);              // ds_read slot swizzle
    const int aRow = wm * 128;
    const int bRow = wn * 64;
    const int m0   = blockIdx.y * 256;
    const int n0   = blockIdx.x * 256;
    const int rbase = w * 16 + (lane >> 2);             // row within piece
    const int ssw   = ((lane & 3) ^ ((lane >> 3) & 3)) * 8; // src k-chunk swz

    f32x4 acc[8][4] = {};

    auto stage = [&](const ushort_t* __restrict__ g, int grow0, int kcol,
                     int regUS) {
        #pragma unroll
        for (int q = 0; q < 2; ++q) {
            const ushort_t* src =
                g + (size_t)(grow0 + q * 128 + rbase) * KIN + kcol + ssw;
            GLDS(src, smem + regUS + q * 4096 + w * 512);
        }
    };

    // prologue: tile0 kh0 (A,B), tile0 kh1 (A,B), tile1 kh0 (A,B) = 12 loads
    stage(Ah,  m0, 0,  0);
    stage(BTh, n0, 0,  32768);
    stage(Ah,  m0, 32, 8192);
    stage(BTh, n0, 32, 32768 + 8192);
    stage(Ah,  m0, 64, 16384);
    stage(BTh, n0, 64, 32768 + 16384);
    asm volatile("s_waitcnt vmcnt(8)" ::: "memory");    // tile0 kh0 resident
    BAR();

    bf16x8 fA[4], fB[4];

    for (int t = 0; t < KTI - 1; ++t) {
        const int bf = t & 1, bn = bf ^ 1;
        const ushort_t* A0 = smem + (bf * 2 + 0) * 8192;
        const ushort_t* A1 = smem + (bf * 2 + 1) * 8192;
        const ushort_t* B0 = smem + 32768 + (bf * 2 + 0) * 8192;
        const ushort_t* B1 = smem + 32768 + (bf * 2 + 1) * 8192;
        const int kc1 = (t + 1) * 64, kc2 = (t + 2) * 64;
        const bool st2 = (t + 2 < KTI);

        // phase 0: kh0, m-frags 0-3; issue A(t+1,kh1)
        LDFRAG_B(B0);
        LDFRAG_A(A0, 0);
        stage(Ah, m0, kc1 + 32, (bn * 2 + 1) * 8192);
        BAR(); LGKM0();
        MFMA_QUAD(0);
        BAR();

        // phase 1: kh0, m-frags 4-7; issue B(t+1,kh1); guard (t,kh1) for p2
        LDFRAG_A(A0, 4);
        stage(BTh, n0, kc1 + 32, 32768 + (bn * 2 + 1) * 8192);
        BAR(); LGKM0();
        MFMA_QUAD(4);
        asm volatile("s_waitcnt vmcnt(8)" ::: "memory");
        BAR();
        __builtin_amdgcn_sched_barrier(0);   // kh0 slot recycles next phase

        // phase 2: kh1, m-frags 0-3; issue A(t+2,kh0) into just-freed slot
        LDFRAG_B(B1);
        LDFRAG_A(A1, 0);
        if (st2) stage(Ah, m0, kc2, (bf * 2 + 0) * 8192);
        BAR(); LGKM0();
        MFMA_QUAD(0);
        BAR();

        // phase 3: kh1, m-frags 4-7; issue B(t+2,kh0); guard (t+1,kh0)
        LDFRAG_A(A1, 4);
        if (st2) stage(BTh, n0, kc2, 32768 + (bf * 2 + 0) * 8192);
        BAR(); LGKM0();
        MFMA_QUAD(4);
        if (t == KTI - 2) { asm volatile("s_waitcnt vmcnt(4)" ::: "memory"); }
        else              { asm volatile("s_waitcnt vmcnt(6)" ::: "memory"); }
        BAR();
        __builtin_amdgcn_sched_barrier(0);
    }

    // last tile (t = KTI-1): no staging; drain kh1 before p2
    {
        const int bf = (KTI - 1) & 1;
        const ushort_t* A0 = smem + (bf * 2 + 0) * 8192;
        const ushort_t* A1 = smem + (bf * 2 + 1) * 8192;
        const ushort_t* B0 = smem + 32768 + (bf * 2 + 0) * 8192;
        const ushort_t* B1 = smem + 32768 + (bf * 2 + 1) * 8192;

        LDFRAG_B(B0);
        LDFRAG_A(A0, 0);
        BAR(); LGKM0();
        MFMA_QUAD(0);
        BAR();

        LDFRAG_A(A0, 4);
        BAR(); LGKM0();
        MFMA_QUAD(4);
        asm volatile("s_waitcnt vmcnt(0)" ::: "memory");
        BAR();

        LDFRAG_B(B1);
        LDFRAG_A(A1, 0);
        BAR(); LGKM0();
        MFMA_QUAD(0);
        BAR();

        LDFRAG_A(A1, 4);
        BAR(); LGKM0();
        MFMA_QUAD(4);
    }

    // epilogue: both halves row-major fp32
    float* dst = (n0 < D_INNER) ? C : AUX;
    const int csub = (n0 < D_INNER) ? 0 : D_INNER;
    #pragma unroll
    for (int mf = 0; mf < 8; ++mf) {
        int row0 = m0 + aRow + mf * 16 + fk * 4;
        #pragma unroll
        for (int nf = 0; nf < 4; ++nf) {
            int col = n0 + bRow + nf * 16 + fm - csub;
            #pragma unroll
            for (int r = 0; r < 4; ++r)
                dst[(size_t)(row0 + r) * D_INNER + col] = acc[mf][nf][r];
        }
    }
}

// ---------------------------------------------------------------------------
// 256x128-tile 8-phase 2-term bf16 GEMM for the out-projection.
// ---------------------------------------------------------------------------
#define KOUT 2048
#define NTOUT 16                // K-slice 1024 / 64

__global__ __launch_bounds__(512, 2) void gemm256_outproj(
    const ushort_t* __restrict__ Ah, const ushort_t* __restrict__ BTh,
    const ushort_t* __restrict__ BTl, float* __restrict__ P)
{
    // regions (ushort units): A[bf][kh]=(bf*2+kh)*8192 (0..32768)
    // Bh[bf][kh]=32768+(bf*2+kh)*4096 ; Bl[bf][kh]=49152+(bf*2+kh)*4096
    __shared__ __align__(1024) ushort_t smem[65536];   // 128 KiB
    const int tid  = threadIdx.x;
    const int lane = tid & 63;
    const int w    = tid >> 6;
    const int wm   = w & 3;              // M quarter
    const int wn   = w >> 2;             // N half
    const int fm   = lane & 15, fk = lane >> 4;
    const int swz  = fk ^ ((fm >> 1) & 3);
    const int aRow = wm * 64;
    const int bRow = wn * 64;
    const int ks   = blockIdx.x >> 3;
    const int n0   = (blockIdx.x & 7) * 128;
    const int m0   = blockIdx.y * 256;
    const int kb   = ks * (KOUT / OKSPL);
    const int rbase = w * 16 + (lane >> 2);             // 0..127
    const int ssw   = ((lane & 3) ^ ((lane >> 3) & 3)) * 8;

    f32x4 acc[4][4] = {};

    auto stageA = [&](int t, int kh) {   // 2 pieces (256 rows x 32)
        const int kcol = kb + t * 64 + kh * 32;
        const int reg = ((t & 1) * 2 + kh) * 8192;
        #pragma unroll
        for (int q = 0; q < 2; ++q) {
            const ushort_t* src =
                Ah + (size_t)(m0 + q * 128 + rbase) * KOUT + kcol + ssw;
            GLDS(src, smem + reg + q * 4096 + w * 512);
        }
    };
    auto stageB = [&](const ushort_t* __restrict__ B, int base, int t, int kh) {
        const int kcol = kb + t * 64 + kh * 32;
        const int reg = base + ((t & 1) * 2 + kh) * 4096;
        const ushort_t* src = B + (size_t)(n0 + rbase) * KOUT + kcol + ssw;
        GLDS(src, smem + reg + w * 512);
    };

    // prologue: tile0 pieces in ledger order
    stageA(0, 0);                 // O1,O2
    stageA(0, 1);                 // O3,O4
    stageB(BTh, 32768, 0, 0);     // O5
    stageB(BTh, 32768, 0, 1);     // O6
    stageB(BTl, 49152, 0, 0);     // O7
    stageB(BTl, 49152, 0, 1);     // O8
    asm volatile("s_waitcnt vmcnt(3)" ::: "memory");    // O1..O5 resident
    BAR();

    bf16x8 fA[4], fB[4];

    for (int t = 0; t < NTOUT - 1; ++t) {
        const int bf = t & 1;
        const ushort_t* A0  = smem + (bf * 2 + 0) * 8192;
        const ushort_t* A1  = smem + (bf * 2 + 1) * 8192;
        const ushort_t* Bh0 = smem + 32768 + (bf * 2 + 0) * 4096;
        const ushort_t* Bh1 = smem + 32768 + (bf * 2 + 1) * 4096;
        const ushort_t* Bl0 = smem + 49152 + (bf * 2 + 0) * 4096;
        const ushort_t* Bl1 = smem + 49152 + (bf * 2 + 1) * 4096;

        // p0: kh0 x Bh; issue A(t+1) kh0
        LDFRAG_B(Bh0);
        LDFRAG_A(A0, 0);
        stageA(t + 1, 0);
        BAR(); LGKM0();
        MFMA_QUAD(0);
        asm volatile("s_waitcnt vmcnt(3)" ::: "memory");
        BAR();
        __builtin_amdgcn_sched_barrier(0);

        // p1: kh0 x Bl (A-frags reused); issue A(t+1) kh1
        LDFRAG_B(Bl0);
        stageA(t + 1, 1);
        BAR(); LGKM0();
        MFMA_QUAD(0);
        BAR();

        // p2: kh1 x Bh; issue Bh(t+1) both kh
        LDFRAG_B(Bh1);
        LDFRAG_A(A1, 0);
        stageB(BTh, 32768, t + 1, 0);
        stageB(BTh, 32768, t + 1, 1);
        BAR(); LGKM0();
        MFMA_QUAD(0);
        asm volatile("s_waitcnt vmcnt(6)" ::: "memory");
        BAR();
        __builtin_amdgcn_sched_barrier(0);

        // p3: kh1 x Bl; issue Bl(t+1) both kh
        LDFRAG_B(Bl1);
        stageB(BTl, 49152, t + 1, 0);
        stageB(BTl, 49152, t + 1, 1);
        BAR(); LGKM0();
        MFMA_QUAD(0);
        asm volatile("s_waitcnt vmcnt(3)" ::: "memory");
        BAR();
        __builtin_amdgcn_sched_barrier(0);
    }

    // last tile (no staging); entry outstanding: Bh_k1, Bl_k0, Bl_k1
    {
        const int bf = (NTOUT - 1) & 1;
        const ushort_t* A0  = smem + (bf * 2 + 0) * 8192;
        const ushort_t* A1  = smem + (bf * 2 + 1) * 8192;
        const ushort_t* Bh0 = smem + 32768 + (bf * 2 + 0) * 4096;
        const ushort_t* Bh1 = smem + 32768 + (bf * 2 + 1) * 4096;
        const ushort_t* Bl0 = smem + 49152 + (bf * 2 + 0) * 4096;
        const ushort_t* Bl1 = smem + 49152 + (bf * 2 + 1) * 4096;

        LDFRAG_B(Bh0);
        LDFRAG_A(A0, 0);
        BAR(); LGKM0();
        MFMA_QUAD(0);
        asm volatile("s_waitcnt vmcnt(1)" ::: "memory");
        BAR();

        LDFRAG_B(Bl0);
        BAR(); LGKM0();
        MFMA_QUAD(0);
        BAR();

        LDFRAG_B(Bh1);
        LDFRAG_A(A1, 0);
        BAR(); LGKM0();
        MFMA_QUAD(0);
        asm volatile("s_waitcnt vmcnt(0)" ::: "memory");
        BAR();

        LDFRAG_B(Bl1);
        BAR(); LGKM0();
        MFMA_QUAD(0);
    }

    // epilogue: partial P[ks][m][n] row-major
    float* Pq = P + (size_t)ks * M_TOT * D_MODEL;
    #pragma unroll
    for (int mf = 0; mf < 4; ++mf) {
        int row0 = m0 + aRow + mf * 16 + fk * 4;
        #pragma unroll
        for (int nf = 0; nf < 4; ++nf) {
            int col = n0 + bRow + nf * 16 + fm;
            #pragma unroll
            for (int r = 0; r < 4; ++r)
                Pq[(size_t)(row0 + r) * D_MODEL + col] = acc[mf][nf][r];
        }
    }
}

// ---------------------------------------------------------------------------
// Split-bf16 MFMA GEMM, BT[N][K] pre-transposed, 128x128 tile, 4 waves, BK=32.
// MODE 3: xproj K-split (KSPL).  MODE 5: dtproj (bias+softplus, row-major).
// ---------------------------------------------------------------------------
template <int MODE, int TERMS>
__global__ __launch_bounds__(256) void gemm_bf16s(
    const ushort_t* __restrict__ Ah, const ushort_t* __restrict__ Al,
    const ushort_t* __restrict__ BTh, const ushort_t* __restrict__ BTl,
    float* __restrict__ C, float* __restrict__ AUX, int M, int N, int K)
{
    __shared__ __align__(16) ushort_t smem[4 * 128 * 32];   // Ah|Al|Bh|Bl tiles
    ushort_t* sAh = smem;
    ushort_t* sAl = smem + 4096;
    ushort_t* sBh = smem + 8192;
    ushort_t* sBl = smem + 12288;
    const int tid = threadIdx.x;
    const int lane = tid & 63;
    const int m0 = blockIdx.y * 128;
    int ks = 0, nblk = blockIdx.x;
    if (MODE == 3) { ks = blockIdx.x; nblk = 0; }
    const int n0 = nblk * 128;
    const int wave = tid >> 6;
    const int mw = (wave & 1) * 64, nw = (wave >> 1) * 64;
    const int fm = lane & 15, fk = lane >> 4;
    const int swz = fk ^ ((fm >> 1) & 3);

    f32x4 acc[4][4] = {};

    const int r_st0 = tid >> 2, cp0 = tid & 3;
    const int r_st1 = (256 + tid) >> 2, cp1 = tid & 3;
    const int cl0 = cp0 ^ ((r_st0 >> 1) & 3);
    const int cl1 = cp1 ^ ((r_st1 >> 1) & 3);
    const int ldsb0 = (tid & ~63) * 16;
    const int ldsb1 = (256 + (tid & ~63)) * 16;

    const int kbeg = (MODE == 3) ? ks * (K / KSPL) : 0;
    const int kend = (MODE == 3) ? kbeg + K / KSPL : K;

    for (int k0 = kbeg; k0 < kend; k0 += 32) {
        __syncthreads();
        {
            size_t ga0 = (size_t)(m0 + r_st0) * K + k0 + cl0 * 8;
            size_t ga1 = (size_t)(m0 + r_st1) * K + k0 + cl1 * 8;
            size_t gb0 = (size_t)(n0 + r_st0) * K + k0 + cl0 * 8;
            size_t gb1 = (size_t)(n0 + r_st1) * K + k0 + cl1 * 8;
            GLDS(Ah + ga0, (char*)sAh + ldsb0);
            GLDS(Ah + ga1, (char*)sAh + ldsb1);
            if (TERMS >= 3) {
                GLDS(Al + ga0, (char*)sAl + ldsb0);
                GLDS(Al + ga1, (char*)sAl + ldsb1);
            }
            GLDS(BTh + gb0, (char*)sBh + ldsb0);
            GLDS(BTh + gb1, (char*)sBh + ldsb1);
            if (TERMS >= 2) {
                GLDS(BTl + gb0, (char*)sBl + ldsb0);
                GLDS(BTl + gb1, (char*)sBl + ldsb1);
            }
        }
        __syncthreads();

        bf16x8 fAh[4], fAl[4], fBh[4], fBl[4];
        #pragma unroll
        for (int t = 0; t < 4; ++t) {
            int ra = (mw + t * 16 + fm) * 32 + swz * 8;
            int rb = (nw + t * 16 + fm) * 32 + swz * 8;
            fAh[t] = *reinterpret_cast<const bf16x8*>(&sAh[ra]);
            if (TERMS >= 3) fAl[t] = *reinterpret_cast<const bf16x8*>(&sAl[ra]);
            fBh[t] = *reinterpret_cast<const bf16x8*>(&sBh[rb]);
            if (TERMS >= 2) fBl[t] = *reinterpret_cast<const bf16x8*>(&sBl[rb]);
        }
        #pragma unroll
        for (int i = 0; i < 4; ++i)
            #pragma unroll
            for (int j = 0; j < 4; ++j) {
                acc[i][j] = __builtin_amdgcn_mfma_f32_16x16x32_bf16(fAh[i], fBh[j], acc[i][j], 0, 0, 0);
                if (TERMS >= 3)
                    acc[i][j] = __builtin_amdgcn_mfma_f32_16x16x32_bf16(fAl[i], fBh[j], acc[i][j], 0, 0, 0);
                if (TERMS >= 2)
                    acc[i][j] = __builtin_amdgcn_mfma_f32_16x16x32_bf16(fAh[i], fBl[j], acc[i][j], 0, 0, 0);
            }
    }

    float* Cq = (MODE == 3) ? C + (size_t)ks * M * N : C;
    #pragma unroll
    for (int i = 0; i < 4; ++i) {
        int row0 = m0 + mw + i * 16 + fk * 4;
        #pragma unroll
        for (int j = 0; j < 4; ++j) {
            int col = n0 + nw + j * 16 + fm;
            if (MODE == 5) {
                const float* bias = (const float*)AUX;
                float bc_ = bias[col];
                #pragma unroll
                for (int r = 0; r < 4; ++r) {
                    float t = acc[i][j][r] + bc_;
                    C[(size_t)(row0 + r) * N + col] =
                        fmaxf(t, 0.f) + log1pf(__expf(-fabsf(t)));
                }
            } else {
                #pragma unroll
                for (int r = 0; r < 4; ++r)
                    Cq[(size_t)(row0 + r) * N + col] = acc[i][j][r];
            }
        }
    }
}

// ---------------------------------------------------------------------------
// xproj split-K reduce: dbc = sum_ks dbcp[ks]; dbch bf16 for dtproj A.
// ---------------------------------------------------------------------------
__global__ __launch_bounds__(256) void xproj_red_k(
    const float* __restrict__ dbcp, float* __restrict__ dbc,
    ushort_t* __restrict__ dbch)
{
    int g = blockIdx.x * 256 + threadIdx.x;      // over 4096*128
    int m = g >> 7, c = g & 127;
    float s = 0.f;
    #pragma unroll
    for (int ks = 0; ks < KSPL; ++ks)
        s += dbcp[(size_t)ks * M_TOT * DBC_STRIDE + g];
    dbc[g] = s;
    if (c < 64)
        dbch[(size_t)m * 64 + c] = f2bf_rne(s);
}

// ---------------------------------------------------------------------------
// out-proj split-K reduce: out = p0 + p1 (float4).
// ---------------------------------------------------------------------------
__global__ __launch_bounds__(256) void outred_k(
    const float* __restrict__ p, float* __restrict__ out)
{
    int i4 = (blockIdx.x * 256 + threadIdx.x) * 4;
    f32x4 a = *reinterpret_cast<const f32x4*>(p + i4);
    f32x4 b = *reinterpret_cast<const f32x4*>(p + (size_t)M_TOT * D_MODEL + i4);
    *reinterpret_cast<f32x4*>(out + i4) = a + b;
}

// ---------------------------------------------------------------------------
// x -> xh bf16 (hi only), elementwise.
// ---------------------------------------------------------------------------
__global__ __launch_bounds__(256) void cast_h_k(
    const float* __restrict__ X, ushort_t* __restrict__ Xh)
{
    int i4 = (blockIdx.x * 256 + threadIdx.x) * 4;
    float4 v = *reinterpret_cast<const float4*>(X + i4);
    ushort2 a = make_ushort2(f2bf_rne(v.x), f2bf_rne(v.y));
    ushort2 b = make_ushort2(f2bf_rne(v.z), f2bf_rne(v.w));
    *reinterpret_cast<ushort2*>(Xh + i4)     = a;
    *reinterpret_cast<ushort2*>(Xh + i4 + 2) = b;
}

// ---------------------------------------------------------------------------
// W[K][N] fp32 -> WT[N][K] bf16 hi/lo (tiled transpose, exact dims).
// ---------------------------------------------------------------------------
__global__ __launch_bounds__(256) void transpose_cast_k(
    const float* __restrict__ W, ushort_t* __restrict__ Th, ushort_t* __restrict__ Tl,
    int K, int N)
{
    __shared__ float tile[32][33];
    int n0 = blockIdx.x * 32, k0 = blockIdx.y * 32;
    int tx = threadIdx.x & 31, ty = threadIdx.x >> 5;
    #pragma unroll
    for (int i = 0; i < 32; i += 8)
        tile[ty + i][tx] = W[(size_t)(k0 + ty + i) * N + n0 + tx];
    __syncthreads();
    #pragma unroll
    for (int i = 0; i < 32; i += 8) {
        float v = tile[tx][ty + i];
        ushort_t h = f2bf_rne(v);
        ushort_t l = f2bf_rne(v - bf2f(h));
        size_t o = (size_t)(n0 + ty + i) * K + k0 + tx;
        Th[o] = h; Tl[o] = l;
    }
}

// ---------------------------------------------------------------------------
// W[K][N] fp32 -> WT[Npad][K] bf16 hi only, zero-padded rows N..Npad.
// ---------------------------------------------------------------------------
__global__ __launch_bounds__(256) void transpose_cast_pad_k(
    const float* __restrict__ W, ushort_t* __restrict__ Th, int K, int N)
{
    __shared__ float tile[32][33];
    int n0 = blockIdx.x * 32, k0 = blockIdx.y * 32;
    int tx = threadIdx.x & 31, ty = threadIdx.x >> 5;
    #pragma unroll
    for (int i = 0; i < 32; i += 8)
        tile[ty + i][tx] = (n0 + tx < N) ? W[(size_t)(k0 + ty + i) * N + n0 + tx] : 0.f;
    __syncthreads();
    #pragma unroll
    for (int i = 0; i < 32; i += 8) {
        float v = tile[tx][ty + i];
        size_t o = (size_t)(n0 + ty + i) * K + k0 + tx;
        Th[o] = f2bf_rne(v);
    }
}

// ---------------------------------------------------------------------------
// Depthwise causal conv + bias + SiLU. Reads compact xbuf[m][2048].
// Outputs xinh [m][d] bf16 (xproj A, 1-term) and xf [m][d] fp32 (scan).
// ---------------------------------------------------------------------------
__global__ __launch_bounds__(256) void conv_silu_k(
    const float* __restrict__ xbuf, const float* __restrict__ Wc,
    const float* __restrict__ bc, ushort_t* __restrict__ xinh,
    float* __restrict__ xf)
{
    __shared__ float tile[67][64];
    const int c0 = blockIdx.x * 64;
    const int m0 = blockIdx.y * 64;
    const int bstart = m0 & ~(LSEQ - 1);
    const int tid = threadIdx.x;

    for (int e = tid; e < 67 * 64; e += 256) {
        int r = e >> 6, c = e & 63;
        int g = m0 - 3 + r;
        tile[r][c] = (g >= bstart) ? xbuf[(size_t)g * D_INNER + c0 + c] : 0.f;
    }
    __syncthreads();

    const int c_l = tid & 63, mg = tid >> 6;
    const int c = c0 + c_l;
    const float w0 = Wc[c], w1 = Wc[D_INNER + c];
    const float w2 = Wc[2 * D_INNER + c], w3 = Wc[3 * D_INNER + c];
    const float bb = bc[c];
    #pragma unroll
    for (int mi = 0; mi < 16; ++mi) {
        int r = mg * 16 + mi;
        float acc = bb + tile[r][c_l] * w0 + tile[r + 1][c_l] * w1
                       + tile[r + 2][c_l] * w2 + tile[r + 3][c_l] * w3;
        float sv = acc / (1.f + __expf(-acc));
        xinh[(size_t)(m0 + r) * D_INNER + c] = f2bf_rne(sv);
        xf[(size_t)(m0 + r) * D_INNER + c] = sv;
    }
}

// ---------------------------------------------------------------------------
// Chunked selective scan, LDS double-buffered + counted-vmcnt version.
// One thread per channel d; 16 states in VGPRs; dt/x(/z) staged to LDS in
// 8-row groups, double-buffered, prefetched one group ahead with counted
// vmcnt (never drain-0 mid-loop); B/C for the whole 64-row chunk staged once
// in the prologue (broadcast reads).  Per-wave piece counts are uniform so
// counted vmcnt is valid for every wave.
// Pass 1: chunk summaries asum (log2 domain), s_end.
// ---------------------------------------------------------------------------
__global__ __launch_bounds__(256) void scan_sum_k4(
    const float* __restrict__ dtf, const float* __restrict__ xf,
    const float* __restrict__ dbc, const float* __restrict__ A_log,
    float* __restrict__ asumb, float* __restrict__ sendb)
{
    __shared__ float sdt[2][8][256];
    __shared__ float sx[2][8][256];
    __shared__ float sB[64][16];          // B for the whole chunk (4 KB)
    const int tid = threadIdx.x;
    const int lane = tid & 63;
    const int w = tid >> 6;
    const int c0 = blockIdx.x << 8;
    const int ck = blockIdx.y;
    const int b  = blockIdx.z;
    const size_t mbase = (size_t)b * LSEQ + (size_t)ck * CH;
    const int d = c0 + tid;

    // stage group G (8 rows) into buffer bf: 4 calls per wave (dt 2 + x 2)
    auto stageG = [&](int G, int bf) {
        #pragma unroll
        for (int p = 0; p < 2; ++p) {
            const int r = w + p * 4;
            const size_t g = (mbase + G * 8 + r) * D_INNER + c0 + lane * 4;
            GLDS(dtf + g, &sdt[bf][r][0]);
            GLDS(xf + g,  &sx[bf][r][0]);
        }
    };

    // prologue: B chunk (1 call/wave) + g0 (4) + g1 (4) = 9 outstanding
    {
        const int rbc = w * 16 + (lane >> 2);
        GLDS(dbc + (mbase + rbc) * DBC_STRIDE + 64 + (lane & 3) * 4,
             &sB[w * 16][0]);
    }
    stageG(0, 0);
    stageG(1, 1);

    float AdnL2[16];
    #pragma unroll
    for (int n = 0; n < 16; ++n)
        AdnL2[n] = -__expf(A_log[d * D_STATE + n]) * LOG2E;

    float s[16] = {};
    float asum[16] = {};

    asm volatile("s_waitcnt vmcnt(4)" ::: "memory");   // B + g0 resident
    BAR();

    for (int G = 0; G < 8; ++G) {
        const int bf = G & 1;
        #pragma unroll
        for (int t = 0; t < 8; ++t) {
            const int rr = G * 8 + t;
            const float dv = sdt[bf][t][tid];
            const float xv = sx[bf][t][tid];
            const float p  = dv * xv;
            #pragma unroll
            for (int n = 0; n < 16; ++n) {
                float a = fmaxf(dv * AdnL2[n], NLOG2E10);
                asum[n] += a;
                float e = fexp2(a);
                s[n] = clip10(fmaf(s[n], e, p * sB[rr][n]));
            }
        }
        BAR();                                  // all waves done with buf bf
        if (G + 2 < 8) {
            stageG(G + 2, bf);                  // refill just-freed buffer
            asm volatile("s_waitcnt vmcnt(4)" ::: "memory");  // g+1 resident
        } else if (G == 6) {
            asm volatile("s_waitcnt vmcnt(0)" ::: "memory");  // g7 resident
        }
        BAR();
        __builtin_amdgcn_sched_barrier(0);
    }

    #pragma unroll
    for (int n = 0; n < 16; ++n) {
        size_t o = (((size_t)(b * NCH + ck) * 16) + n) * D_INNER + d;
        asumb[o] = asum[n];
        sendb[o] = s[n];
    }
}

// ---------------------------------------------------------------------------
// Pass 2: sequential combine over chunk summaries -> entry state per chunk.
// ---------------------------------------------------------------------------
__global__ __launch_bounds__(256) void scan_fix_k2(
    const float* __restrict__ asumb, const float* __restrict__ sendb,
    float* __restrict__ sinb)
{
    int g = blockIdx.x * 256 + threadIdx.x;     // d + 2048*(n + 16*b)
    int d = g & (D_INNER - 1);
    int n = (g >> 11) & 15;
    int b = g >> 15;
    float s = 0.f;
    for (int ck = 0; ck < NCH; ++ck) {
        size_t idx = (((size_t)(b * NCH + ck) * 16) + n) * D_INNER + d;
        sinb[idx] = s;
        s = clip10(fmaf(s, fexp2(asumb[idx]), sendb[idx]));
    }
}

// ---------------------------------------------------------------------------
// Pass 3: recompute local scan from entry state, n-sum in registers (4-way
// partials), gate, store y bf16 [m][d].  Same dbuf+counted-vmcnt structure.
// ---------------------------------------------------------------------------
__global__ __launch_bounds__(256) void scan_apply_k4(
    const float* __restrict__ dtf, const float* __restrict__ xf,
    const float* __restrict__ dbc, const float* __restrict__ zf,
    const float* __restrict__ sinb, const float* __restrict__ A_log,
    const float* __restrict__ Dv, ushort_t* __restrict__ Yh)
{
    __shared__ float sdt[2][8][256];
    __shared__ float sx[2][8][256];
    __shared__ float sz[2][8][256];
    __shared__ float sBC[64][32];         // B|C for the whole chunk (8 KB)
    const int tid = threadIdx.x;
    const int lane = tid & 63;
    const int w = tid >> 6;
    const int c0 = blockIdx.x << 8;
    const int ck = blockIdx.y;
    const int b  = blockIdx.z;
    const size_t mbase = (size_t)b * LSEQ + (size_t)ck * CH;
    const int d = c0 + tid;

    // stage group G (8 rows) into buffer bf: 6 calls per wave (dt/x/z x 2)
    auto stageG = [&](int G, int bf) {
        #pragma unroll
        for (int p = 0; p < 2; ++p) {
            const int r = w + p * 4;
            const size_t g = (mbase + G * 8 + r) * D_INNER + c0 + lane * 4;
            GLDS(dtf + g, &sdt[bf][r][0]);
            GLDS(xf + g,  &sx[bf][r][0]);
            GLDS(zf + g,  &sz[bf][r][0]);
        }
    };

    // prologue: BC chunk (2 calls/wave) + g0 (6) + g1 (6) = 14 outstanding
    #pragma unroll
    for (int p = 0; p < 2; ++p) {
        const int rbc = w * 16 + p * 8 + (lane >> 3);
        GLDS(dbc + (mbase + rbc) * DBC_STRIDE + 64 + (lane & 7) * 4,
             &sBC[w * 16 + p * 8][0]);
    }
    stageG(0, 0);
    stageG(1, 1);

    float AdnL2[16];
    #pragma unroll
    for (int n = 0; n < 16; ++n)
        AdnL2[n] = -__expf(A_log[d * D_STATE + n]) * LOG2E;
    const float Dd = Dv[d];

    float s[16];
    #pragma unroll
    for (int n = 0; n < 16; ++n)
        s[n] = sinb[(((size_t)(b * NCH + ck) * 16) + n) * D_INNER + d];

    asm volatile("s_waitcnt vmcnt(6)" ::: "memory");   // BC + g0 resident
    BAR();

    for (int G = 0; G < 8; ++G) {
        const int bf = G & 1;
        #pragma unroll
        for (int t = 0; t < 8; ++t) {
            const int rr = G * 8 + t;
            const float dv = sdt[bf][t][tid];
            const float xv = sx[bf][t][tid];
            const float p  = dv * xv;
            float y0 = Dd * xv, y1 = 0.f, y2 = 0.f, y3 = 0.f;
            #pragma unroll
            for (int n = 0; n < 16; n += 4) {
                float a0 = fmaxf(dv * AdnL2[n + 0], NLOG2E10);
                float a1 = fmaxf(dv * AdnL2[n + 1], NLOG2E10);
                float a2 = fmaxf(dv * AdnL2[n + 2], NLOG2E10);
                float a3 = fmaxf(dv * AdnL2[n + 3], NLOG2E10);
                s[n + 0] = clip10(fmaf(s[n + 0], fexp2(a0), p * sBC[rr][n + 0]));
                s[n + 1] = clip10(fmaf(s[n + 1], fexp2(a1), p * sBC[rr][n + 1]));
                s[n + 2] = clip10(fmaf(s[n + 2], fexp2(a2), p * sBC[rr][n + 2]));
                s[n + 3] = clip10(fmaf(s[n + 3], fexp2(a3), p * sBC[rr][n + 3]));
                y0 = fmaf(s[n + 0], sBC[rr][16 + n + 0], y0);
                y1 = fmaf(s[n + 1], sBC[rr][16 + n + 1], y1);
                y2 = fmaf(s[n + 2], sBC[rr][16 + n + 2], y2);
                y3 = fmaf(s[n + 3], sBC[rr][16 + n + 3], y3);
            }
            const float y = (y0 + y1) + (y2 + y3);
            const float zz = sz[bf][t][tid];
            const float gate = zz * frcp(1.f + fexp2(zz * -LOG2E));
            Yh[(mbase + rr) * D_INNER + d] = f2bf_rne(y * gate);
        }
        BAR();
        if (G + 2 < 8) {
            stageG(G + 2, bf);
            asm volatile("s_waitcnt vmcnt(6)" ::: "memory");
        } else if (G == 6) {
            asm volatile("s_waitcnt vmcnt(0)" ::: "memory");
        }
        BAR();
        __builtin_amdgcn_sched_barrier(0);
    }
}

// ---------------------------------------------------------------------------
extern "C" void kernel_launch(void* const* d_in, const int* in_sizes, int n_in,
                              void* d_out, int out_size, void* d_ws, size_t ws_size,
                              hipStream_t stream)
{
    const float* x       = (const float*)d_in[0];
    const float* W_in    = (const float*)d_in[1];
    const float* W_conv  = (const float*)d_in[2];
    const float* b_conv  = (const float*)d_in[3];
    const float* W_xproj = (const float*)d_in[4];
    const float* W_dt    = (const float*)d_in[5];
    const float* b_dt    = (const float*)d_in[6];
    const float* A_log   = (const float*)d_in[7];
    const float* Dv      = (const float*)d_in[8];
    const float* W_out   = (const float*)d_in[9];
    float* out = (float*)d_out;

    // fp32 region
    float* xbuf = (float*)d_ws;                              // [4096][2048]
    float* zf   = xbuf + (size_t)M_TOT * D_INNER;            // [4096][2048] z row-major
    float* dbc  = zf + (size_t)M_TOT * D_INNER;              // [4096][128]
    float* BCT  = dbc + (size_t)M_TOT * DBC_STRIDE;          // (unused slot)
    // bf16 region (layout slots; several aliased below)
    ushort_t* xh     = (ushort_t*)(BCT + (size_t)32 * M_TOT);
    ushort_t* xl     = xh + (size_t)M_TOT * D_MODEL;          // (slot)
    ushort_t* WinTh  = xl + (size_t)M_TOT * D_MODEL;          // [4096][1024]
    ushort_t* WinTl  = WinTh + (size_t)2 * D_INNER * D_MODEL; // (slot)
    ushort_t* WoutTh = WinTl + (size_t)2 * D_INNER * D_MODEL; // [1024][2048]
    ushort_t* WoutTl = WoutTh + (size_t)D_MODEL * D_INNER;
    ushort_t* WxTh   = WoutTl + (size_t)D_MODEL * D_INNER;    // [128][2048]
    ushort_t* WxTl   = WxTh + (size_t)DBC_STRIDE * D_INNER;   // (slot)
    ushort_t* xinh   = WxTl + (size_t)DBC_STRIDE * D_INNER;   // [4096][2048]
    ushort_t* xinl   = xinh + (size_t)M_TOT * D_INNER;        // (slot)
    ushort_t* yh     = xinl + (size_t)M_TOT * D_INNER;        // [4096][2048]
    ushort_t* yl     = yh + (size_t)M_TOT * D_INNER;          // (slot)
    ushort_t* WdtTh  = yl + (size_t)M_TOT * D_INNER;          // [2048][64]
    ushort_t* dbch   = WdtTh + (size_t)D_INNER * DT_RANK;     // [4096][64]
    // aliases (stream-ordered reuse of dead regions):
    float* xf   = (float*)xh;    // [4096][2048] over xh|xl|WinTh|WinTl (dead after gemm#1)
    float* dtf  = (float*)xinh;  // [4096][2048] over xinh|xinl (dead after xproj gemm)
    float* dbcp = (float*)yh;    // [8][4096][128] over yh|yl (dead until scan_apply)
    float* pout = (float*)xh;    // [2][4096][1024] over xf region (dead after scan)
    const size_t NSUM = (size_t)NBATCH * NCH * D_INNER * D_STATE;
    float* asumb = xbuf;         // over xbuf (dead after conv)
    float* sendb = xbuf + NSUM;
    float* sinb  = xbuf + 2 * NSUM;

    // precompute: casts + weight transposes
    cast_h_k<<<(M_TOT * D_MODEL) / 1024, 256, 0, stream>>>(x, xh);
    transpose_cast_pad_k<<<dim3((2 * D_INNER) / 32, D_MODEL / 32), 256, 0, stream>>>(
        W_in, WinTh, D_MODEL, 2 * D_INNER);
    transpose_cast_k<<<dim3(D_MODEL / 32, D_INNER / 32), 256, 0, stream>>>(
        W_out, WoutTh, WoutTl, D_INNER, D_MODEL);
    transpose_cast_pad_k<<<dim3(DBC_STRIDE / 32, D_INNER / 32), 256, 0, stream>>>(
        W_xproj, WxTh, D_INNER, DT_RANK + 2 * D_STATE);
    transpose_cast_pad_k<<<dim3(D_INNER / 32, DT_RANK / 32), 256, 0, stream>>>(
        W_dt, WdtTh, DT_RANK, D_INNER);

    // 1) in-proj (256x256 8-phase): x-half -> xbuf, z-half -> zf[m][d]
    gemm256_inproj<<<dim3(16, 16), 512, 0, stream>>>(xh, WinTh, xbuf, zf);
    // 2) conv + silu -> xinh [m][d] bf16 + xf [m][d] fp32
    conv_silu_k<<<dim3(D_INNER / 64, M_TOT / 64), 256, 0, stream>>>(
        xbuf, W_conv, b_conv, xinh, xf);
    // 3) xproj (1-term, K-split x8) -> dbcp partials -> dbc + dbch bf16
    gemm_bf16s<3, 1><<<dim3(KSPL, 32), 256, 0, stream>>>(
        xinh, nullptr, WxTh, nullptr, dbcp, nullptr, M_TOT, DBC_STRIDE, D_INNER);
    xproj_red_k<<<(M_TOT * DBC_STRIDE) / 256, 256, 0, stream>>>(dbcp, dbc, dbch);
    // 4) dtproj via MFMA (MODE 5): dtf[m][d] = softplus(dbch @ WdtT + b_dt)
    gemm_bf16s<5, 1><<<dim3(D_INNER / 128, M_TOT / 128), 256, 0, stream>>>(
        dbch, nullptr, WdtTh, nullptr, dtf, (float*)b_dt, M_TOT, D_INNER, DT_RANK);
    // 5) chunked scan (LDS dbuf + counted vmcnt): sum -> fix -> apply+gate
    scan_sum_k4<<<dim3(D_INNER / 256, NCH, NBATCH), 256, 0, stream>>>(
        dtf, xf, dbc, A_log, asumb, sendb);
    scan_fix_k2<<<(NBATCH * D_STATE * D_INNER) / 256, 256, 0, stream>>>(
        asumb, sendb, sinb);
    scan_apply_k4<<<dim3(D_INNER / 256, NCH, NBATCH), 256, 0, stream>>>(
        dtf, xf, dbc, zf, sinb, A_log, Dv, yh);
    // 6) out-proj (256x128 8-phase 2-term, K-split x2) -> pout partials -> out
    gemm256_outproj<<<dim3(16, 16), 512, 0, stream>>>(yh, WoutTh, WoutTl, pout);
    outred_k<<<(M_TOT * D_MODEL) / 1024, 256, 0, stream>>>(pout, out);
}

// Round 6
// 335.232 us; speedup vs baseline: 2.5918x; 1.0005x over previous
//
#include <hip/hip_runtime.h>
#include <math.h>

#define D_MODEL 1024
#define D_INNER 2048
#define D_STATE 16
#define DT_RANK 64
#define LSEQ 2048
#define NBATCH 2
#define M_TOT (NBATCH * LSEQ)   // 4096 rows total
#define DBC_STRIDE 128          // padded xproj output stride
#define CH 64                   // scan chunk length
#define NCH (LSEQ / CH)         // 32 chunks
#define KSPL 8                  // xproj K-split factor
#define OKSPL 2                 // out-proj K-split factor

typedef unsigned short ushort_t;
typedef unsigned int uint_t;
typedef __attribute__((ext_vector_type(8))) short bf16x8;
typedef __attribute__((ext_vector_type(4))) float f32x4;

__device__ __forceinline__ ushort_t f2bf_rne(float f) {
    uint_t u = __float_as_uint(f);
    u += 0x7fffu + ((u >> 16) & 1u);
    return (ushort_t)(u >> 16);
}
__device__ __forceinline__ float bf2f(ushort_t h) {
    return __uint_as_float(((uint_t)h) << 16);
}
__device__ __forceinline__ float fexp2(float x) {
#if __has_builtin(__builtin_amdgcn_exp2f)
    return __builtin_amdgcn_exp2f(x);
#else
    return exp2f(x);
#endif
}
__device__ __forceinline__ float frcp(float x) {
#if __has_builtin(__builtin_amdgcn_rcpf)
    return __builtin_amdgcn_rcpf(x);
#else
    return 1.f / x;
#endif
}
__device__ __forceinline__ float clip10(float x) {
#if __has_builtin(__builtin_amdgcn_fmed3f)
    return __builtin_amdgcn_fmed3f(x, -10.f, 10.f);
#else
    return fminf(fmaxf(x, -10.f), 10.f);
#endif
}

#define LOG2E 1.44269504f
#define NLOG2E10 -14.4269504f   // -10 * log2(e)

#define BAR()   __builtin_amdgcn_s_barrier()
#define LGKM0() asm volatile("s_waitcnt lgkmcnt(0)" ::: "memory")
#define GLDS(SRC, DST)                                                         \
    __builtin_amdgcn_global_load_lds(                                          \
        (const __attribute__((address_space(1))) void*)(SRC),                  \
        (__attribute__((address_space(3))) void*)(DST), 16, 0, 0)

#define LDFRAG_B(SRC)                                                          \
    _Pragma("unroll")                                                          \
    for (int nf = 0; nf < 4; ++nf)                                             \
        fB[nf] = *reinterpret_cast<const bf16x8*>(                             \
            &(SRC)[(bRow + nf * 16 + fm) * 32 + swz * 8]);

#define LDFRAG_A(SRC, MOFF)                                                    \
    _Pragma("unroll")                                                          \
    for (int mf = 0; mf < 4; ++mf)                                             \
        fA[mf] = *reinterpret_cast<const bf16x8*>(                             \
            &(SRC)[(aRow + (MOFF + mf) * 16 + fm) * 32 + swz * 8]);

#define MFMA_QUAD(MOFF)                                                        \
    __builtin_amdgcn_s_setprio(1);                                             \
    _Pragma("unroll")                                                          \
    for (int mf = 0; mf < 4; ++mf)                                             \
        _Pragma("unroll")                                                      \
        for (int nf = 0; nf < 4; ++nf)                                         \
            acc[MOFF + mf][nf] = __builtin_amdgcn_mfma_f32_16x16x32_bf16(      \
                fA[mf], fB[nf], acc[MOFF + mf][nf], 0, 0, 0);                  \
    __builtin_amdgcn_s_setprio(0);

// ---------------------------------------------------------------------------
// 256x256-tile 8-phase bf16 GEMM for the in-projection (M=4096,N=4096,K=1024).
// ---------------------------------------------------------------------------
#define KIN 1024
#define KTI (KIN / 64)          // 16 K-tiles

__global__ __launch_bounds__(512, 2) void gemm256_inproj(
    const ushort_t* __restrict__ Ah, const ushort_t* __restrict__ BTh,
    float* __restrict__ C, float* __restrict__ AUX)
{
    // regions (ushort units): A[bf][kh] = (bf*2+kh)*8192 ; B = 32768 + same
    __shared__ __align__(1024) ushort_t smem[65536];   // 128 KiB
    const int tid  = threadIdx.x;
    const int lane = tid & 63;
    const int w    = tid >> 6;           // wave 0..7
    const int wm   = w >> 2;             // 0..1  (M half)
    const int wn   = w & 3;              // 0..3  (N quarter)
    const int fm   = lane & 15, fk = lane >> 4;
    const int swz  = fk ^ ((fm >> 1) & 3);              // ds_read slot swizzle
    const int aRow = wm * 128;
    const int bRow = wn * 64;
    const int m0   = blockIdx.y * 256;
    const int n0   = blockIdx.x * 256;
    const int rbase = w * 16 + (lane >> 2);             // row within piece
    const int ssw   = ((lane & 3) ^ ((lane >> 3) & 3)) * 8; // src k-chunk swz

    f32x4 acc[8][4] = {};

    auto stage = [&](const ushort_t* __restrict__ g, int grow0, int kcol,
                     int regUS) {
        #pragma unroll
        for (int q = 0; q < 2; ++q) {
            const ushort_t* src =
                g + (size_t)(grow0 + q * 128 + rbase) * KIN + kcol + ssw;
            GLDS(src, smem + regUS + q * 4096 + w * 512);
        }
    };

    // prologue: tile0 kh0 (A,B), tile0 kh1 (A,B), tile1 kh0 (A,B) = 12 loads
    stage(Ah,  m0, 0,  0);
    stage(BTh, n0, 0,  32768);
    stage(Ah,  m0, 32, 8192);
    stage(BTh, n0, 32, 32768 + 8192);
    stage(Ah,  m0, 64, 16384);
    stage(BTh, n0, 64, 32768 + 16384);
    asm volatile("s_waitcnt vmcnt(8)" ::: "memory");    // tile0 kh0 resident
    BAR();

    bf16x8 fA[4], fB[4];

    for (int t = 0; t < KTI - 1; ++t) {
        const int bf = t & 1, bn = bf ^ 1;
        const ushort_t* A0 = smem + (bf * 2 + 0) * 8192;
        const ushort_t* A1 = smem + (bf * 2 + 1) * 8192;
        const ushort_t* B0 = smem + 32768 + (bf * 2 + 0) * 8192;
        const ushort_t* B1 = smem + 32768 + (bf * 2 + 1) * 8192;
        const int kc1 = (t + 1) * 64, kc2 = (t + 2) * 64;
        const bool st2 = (t + 2 < KTI);

        // phase 0: kh0, m-frags 0-3; issue A(t+1,kh1)
        LDFRAG_B(B0);
        LDFRAG_A(A0, 0);
        stage(Ah, m0, kc1 + 32, (bn * 2 + 1) * 8192);
        BAR(); LGKM0();
        MFMA_QUAD(0);
        BAR();

        // phase 1: kh0, m-frags 4-7; issue B(t+1,kh1); guard (t,kh1) for p2
        LDFRAG_A(A0, 4);
        stage(BTh, n0, kc1 + 32, 32768 + (bn * 2 + 1) * 8192);
        BAR(); LGKM0();
        MFMA_QUAD(4);
        asm volatile("s_waitcnt vmcnt(8)" ::: "memory");
        BAR();
        __builtin_amdgcn_sched_barrier(0);   // kh0 slot recycles next phase

        // phase 2: kh1, m-frags 0-3; issue A(t+2,kh0) into just-freed slot
        LDFRAG_B(B1);
        LDFRAG_A(A1, 0);
        if (st2) stage(Ah, m0, kc2, (bf * 2 + 0) * 8192);
        BAR(); LGKM0();
        MFMA_QUAD(0);
        BAR();

        // phase 3: kh1, m-frags 4-7; issue B(t+2,kh0); guard (t+1,kh0)
        LDFRAG_A(A1, 4);
        if (st2) stage(BTh, n0, kc2, 32768 + (bf * 2 + 0) * 8192);
        BAR(); LGKM0();
        MFMA_QUAD(4);
        if (t == KTI - 2) { asm volatile("s_waitcnt vmcnt(4)" ::: "memory"); }
        else              { asm volatile("s_waitcnt vmcnt(6)" ::: "memory"); }
        BAR();
        __builtin_amdgcn_sched_barrier(0);
    }

    // last tile (t = KTI-1): no staging; drain kh1 before p2
    {
        const int bf = (KTI - 1) & 1;
        const ushort_t* A0 = smem + (bf * 2 + 0) * 8192;
        const ushort_t* A1 = smem + (bf * 2 + 1) * 8192;
        const ushort_t* B0 = smem + 32768 + (bf * 2 + 0) * 8192;
        const ushort_t* B1 = smem + 32768 + (bf * 2 + 1) * 8192;

        LDFRAG_B(B0);
        LDFRAG_A(A0, 0);
        BAR(); LGKM0();
        MFMA_QUAD(0);
        BAR();

        LDFRAG_A(A0, 4);
        BAR(); LGKM0();
        MFMA_QUAD(4);
        asm volatile("s_waitcnt vmcnt(0)" ::: "memory");
        BAR();

        LDFRAG_B(B1);
        LDFRAG_A(A1, 0);
        BAR(); LGKM0();
        MFMA_QUAD(0);
        BAR();

        LDFRAG_A(A1, 4);
        BAR(); LGKM0();
        MFMA_QUAD(4);
    }

    // epilogue: both halves row-major fp32
    float* dst = (n0 < D_INNER) ? C : AUX;
    const int csub = (n0 < D_INNER) ? 0 : D_INNER;
    #pragma unroll
    for (int mf = 0; mf < 8; ++mf) {
        int row0 = m0 + aRow + mf * 16 + fk * 4;
        #pragma unroll
        for (int nf = 0; nf < 4; ++nf) {
            int col = n0 + bRow + nf * 16 + fm - csub;
            #pragma unroll
            for (int r = 0; r < 4; ++r)
                dst[(size_t)(row0 + r) * D_INNER + col] = acc[mf][nf][r];
        }
    }
}

// ---------------------------------------------------------------------------
// 256x128-tile 8-phase 2-term bf16 GEMM for the out-projection.
// ---------------------------------------------------------------------------
#define KOUT 2048
#define NTOUT 16                // K-slice 1024 / 64

__global__ __launch_bounds__(512, 2) void gemm256_outproj(
    const ushort_t* __restrict__ Ah, const ushort_t* __restrict__ BTh,
    const ushort_t* __restrict__ BTl, float* __restrict__ P)
{
    // regions (ushort units): A[bf][kh]=(bf*2+kh)*8192 (0..32768)
    // Bh[bf][kh]=32768+(bf*2+kh)*4096 ; Bl[bf][kh]=49152+(bf*2+kh)*4096
    __shared__ __align__(1024) ushort_t smem[65536];   // 128 KiB
    const int tid  = threadIdx.x;
    const int lane = tid & 63;
    const int w    = tid >> 6;
    const int wm   = w & 3;              // M quarter
    const int wn   = w >> 2;             // N half
    const int fm   = lane & 15, fk = lane >> 4;
    const int swz  = fk ^ ((fm >> 1) & 3);
    const int aRow = wm * 64;
    const int bRow = wn * 64;
    const int ks   = blockIdx.x >> 3;
    const int n0   = (blockIdx.x & 7) * 128;
    const int m0   = blockIdx.y * 256;
    const int kb   = ks * (KOUT / OKSPL);
    const int rbase = w * 16 + (lane >> 2);             // 0..127
    const int ssw   = ((lane & 3) ^ ((lane >> 3) & 3)) * 8;

    f32x4 acc[4][4] = {};

    auto stageA = [&](int t, int kh) {   // 2 pieces (256 rows x 32)
        const int kcol = kb + t * 64 + kh * 32;
        const int reg = ((t & 1) * 2 + kh) * 8192;
        #pragma unroll
        for (int q = 0; q < 2; ++q) {
            const ushort_t* src =
                Ah + (size_t)(m0 + q * 128 + rbase) * KOUT + kcol + ssw;
            GLDS(src, smem + reg + q * 4096 + w * 512);
        }
    };
    auto stageB = [&](const ushort_t* __restrict__ B, int base, int t, int kh) {
        const int kcol = kb + t * 64 + kh * 32;
        const int reg = base + ((t & 1) * 2 + kh) * 4096;
        const ushort_t* src = B + (size_t)(n0 + rbase) * KOUT + kcol + ssw;
        GLDS(src, smem + reg + w * 512);
    };

    // prologue: tile0 pieces in ledger order
    stageA(0, 0);                 // O1,O2
    stageA(0, 1);                 // O3,O4
    stageB(BTh, 32768, 0, 0);     // O5
    stageB(BTh, 32768, 0, 1);     // O6
    stageB(BTl, 49152, 0, 0);     // O7
    stageB(BTl, 49152, 0, 1);     // O8
    asm volatile("s_waitcnt vmcnt(3)" ::: "memory");    // O1..O5 resident
    BAR();

    bf16x8 fA[4], fB[4];

    for (int t = 0; t < NTOUT - 1; ++t) {
        const int bf = t & 1;
        const ushort_t* A0  = smem + (bf * 2 + 0) * 8192;
        const ushort_t* A1  = smem + (bf * 2 + 1) * 8192;
        const ushort_t* Bh0 = smem + 32768 + (bf * 2 + 0) * 4096;
        const ushort_t* Bh1 = smem + 32768 + (bf * 2 + 1) * 4096;
        const ushort_t* Bl0 = smem + 49152 + (bf * 2 + 0) * 4096;
        const ushort_t* Bl1 = smem + 49152 + (bf * 2 + 1) * 4096;

        // p0: kh0 x Bh; issue A(t+1) kh0
        LDFRAG_B(Bh0);
        LDFRAG_A(A0, 0);
        stageA(t + 1, 0);
        BAR(); LGKM0();
        MFMA_QUAD(0);
        asm volatile("s_waitcnt vmcnt(3)" ::: "memory");
        BAR();
        __builtin_amdgcn_sched_barrier(0);

        // p1: kh0 x Bl (A-frags reused); issue A(t+1) kh1
        LDFRAG_B(Bl0);
        stageA(t + 1, 1);
        BAR(); LGKM0();
        MFMA_QUAD(0);
        BAR();

        // p2: kh1 x Bh; issue Bh(t+1) both kh
        LDFRAG_B(Bh1);
        LDFRAG_A(A1, 0);
        stageB(BTh, 32768, t + 1, 0);
        stageB(BTh, 32768, t + 1, 1);
        BAR(); LGKM0();
        MFMA_QUAD(0);
        asm volatile("s_waitcnt vmcnt(6)" ::: "memory");
        BAR();
        __builtin_amdgcn_sched_barrier(0);

        // p3: kh1 x Bl; issue Bl(t+1) both kh
        LDFRAG_B(Bl1);
        stageB(BTl, 49152, t + 1, 0);
        stageB(BTl, 49152, t + 1, 1);
        BAR(); LGKM0();
        MFMA_QUAD(0);
        asm volatile("s_waitcnt vmcnt(3)" ::: "memory");
        BAR();
        __builtin_amdgcn_sched_barrier(0);
    }

    // last tile (no staging); entry outstanding: Bh_k1, Bl_k0, Bl_k1
    {
        const int bf = (NTOUT - 1) & 1;
        const ushort_t* A0  = smem + (bf * 2 + 0) * 8192;
        const ushort_t* A1  = smem + (bf * 2 + 1) * 8192;
        const ushort_t* Bh0 = smem + 32768 + (bf * 2 + 0) * 4096;
        const ushort_t* Bh1 = smem + 32768 + (bf * 2 + 1) * 4096;
        const ushort_t* Bl0 = smem + 49152 + (bf * 2 + 0) * 4096;
        const ushort_t* Bl1 = smem + 49152 + (bf * 2 + 1) * 4096;

        LDFRAG_B(Bh0);
        LDFRAG_A(A0, 0);
        BAR(); LGKM0();
        MFMA_QUAD(0);
        asm volatile("s_waitcnt vmcnt(1)" ::: "memory");
        BAR();

        LDFRAG_B(Bl0);
        BAR(); LGKM0();
        MFMA_QUAD(0);
        BAR();

        LDFRAG_B(Bh1);
        LDFRAG_A(A1, 0);
        BAR(); LGKM0();
        MFMA_QUAD(0);
        asm volatile("s_waitcnt vmcnt(0)" ::: "memory");
        BAR();

        LDFRAG_B(Bl1);
        BAR(); LGKM0();
        MFMA_QUAD(0);
    }

    // epilogue: partial P[ks][m][n] row-major
    float* Pq = P + (size_t)ks * M_TOT * D_MODEL;
    #pragma unroll
    for (int mf = 0; mf < 4; ++mf) {
        int row0 = m0 + aRow + mf * 16 + fk * 4;
        #pragma unroll
        for (int nf = 0; nf < 4; ++nf) {
            int col = n0 + bRow + nf * 16 + fm;
            #pragma unroll
            for (int r = 0; r < 4; ++r)
                Pq[(size_t)(row0 + r) * D_MODEL + col] = acc[mf][nf][r];
        }
    }
}

// ---------------------------------------------------------------------------
// Split-bf16 MFMA GEMM, BT[N][K] pre-transposed, 128x128 tile, 4 waves, BK=32.
// MODE 3: xproj K-split (KSPL).  MODE 5: dtproj (bias+softplus, row-major).
// ---------------------------------------------------------------------------
template <int MODE, int TERMS>
__global__ __launch_bounds__(256) void gemm_bf16s(
    const ushort_t* __restrict__ Ah, const ushort_t* __restrict__ Al,
    const ushort_t* __restrict__ BTh, const ushort_t* __restrict__ BTl,
    float* __restrict__ C, float* __restrict__ AUX, int M, int N, int K)
{
    __shared__ __align__(16) ushort_t smem[4 * 128 * 32];   // Ah|Al|Bh|Bl tiles
    ushort_t* sAh = smem;
    ushort_t* sAl = smem + 4096;
    ushort_t* sBh = smem + 8192;
    ushort_t* sBl = smem + 12288;
    const int tid = threadIdx.x;
    const int lane = tid & 63;
    const int m0 = blockIdx.y * 128;
    int ks = 0, nblk = blockIdx.x;
    if (MODE == 3) { ks = blockIdx.x; nblk = 0; }
    const int n0 = nblk * 128;
    const int wave = tid >> 6;
    const int mw = (wave & 1) * 64, nw = (wave >> 1) * 64;
    const int fm = lane & 15, fk = lane >> 4;
    const int swz = fk ^ ((fm >> 1) & 3);

    f32x4 acc[4][4] = {};

    const int r_st0 = tid >> 2, cp0 = tid & 3;
    const int r_st1 = (256 + tid) >> 2, cp1 = tid & 3;
    const int cl0 = cp0 ^ ((r_st0 >> 1) & 3);
    const int cl1 = cp1 ^ ((r_st1 >> 1) & 3);
    const int ldsb0 = (tid & ~63) * 16;
    const int ldsb1 = (256 + (tid & ~63)) * 16;

    const int kbeg = (MODE == 3) ? ks * (K / KSPL) : 0;
    const int kend = (MODE == 3) ? kbeg + K / KSPL : K;

    for (int k0 = kbeg; k0 < kend; k0 += 32) {
        __syncthreads();
        {
            size_t ga0 = (size_t)(m0 + r_st0) * K + k0 + cl0 * 8;
            size_t ga1 = (size_t)(m0 + r_st1) * K + k0 + cl1 * 8;
            size_t gb0 = (size_t)(n0 + r_st0) * K + k0 + cl0 * 8;
            size_t gb1 = (size_t)(n0 + r_st1) * K + k0 + cl1 * 8;
            GLDS(Ah + ga0, (char*)sAh + ldsb0);
            GLDS(Ah + ga1, (char*)sAh + ldsb1);
            if (TERMS >= 3) {
                GLDS(Al + ga0, (char*)sAl + ldsb0);
                GLDS(Al + ga1, (char*)sAl + ldsb1);
            }
            GLDS(BTh + gb0, (char*)sBh + ldsb0);
            GLDS(BTh + gb1, (char*)sBh + ldsb1);
            if (TERMS >= 2) {
                GLDS(BTl + gb0, (char*)sBl + ldsb0);
                GLDS(BTl + gb1, (char*)sBl + ldsb1);
            }
        }
        __syncthreads();

        bf16x8 fAh[4], fAl[4], fBh[4], fBl[4];
        #pragma unroll
        for (int t = 0; t < 4; ++t) {
            int ra = (mw + t * 16 + fm) * 32 + swz * 8;
            int rb = (nw + t * 16 + fm) * 32 + swz * 8;
            fAh[t] = *reinterpret_cast<const bf16x8*>(&sAh[ra]);
            if (TERMS >= 3) fAl[t] = *reinterpret_cast<const bf16x8*>(&sAl[ra]);
            fBh[t] = *reinterpret_cast<const bf16x8*>(&sBh[rb]);
            if (TERMS >= 2) fBl[t] = *reinterpret_cast<const bf16x8*>(&sBl[rb]);
        }
        #pragma unroll
        for (int i = 0; i < 4; ++i)
            #pragma unroll
            for (int j = 0; j < 4; ++j) {
                acc[i][j] = __builtin_amdgcn_mfma_f32_16x16x32_bf16(fAh[i], fBh[j], acc[i][j], 0, 0, 0);
                if (TERMS >= 3)
                    acc[i][j] = __builtin_amdgcn_mfma_f32_16x16x32_bf16(fAl[i], fBh[j], acc[i][j], 0, 0, 0);
                if (TERMS >= 2)
                    acc[i][j] = __builtin_amdgcn_mfma_f32_16x16x32_bf16(fAh[i], fBl[j], acc[i][j], 0, 0, 0);
            }
    }

    float* Cq = (MODE == 3) ? C + (size_t)ks * M * N : C;
    #pragma unroll
    for (int i = 0; i < 4; ++i) {
        int row0 = m0 + mw + i * 16 + fk * 4;
        #pragma unroll
        for (int j = 0; j < 4; ++j) {
            int col = n0 + nw + j * 16 + fm;
            if (MODE == 5) {
                const float* bias = (const float*)AUX;
                float bc_ = bias[col];
                #pragma unroll
                for (int r = 0; r < 4; ++r) {
                    float t = acc[i][j][r] + bc_;
                    C[(size_t)(row0 + r) * N + col] =
                        fmaxf(t, 0.f) + log1pf(__expf(-fabsf(t)));
                }
            } else {
                #pragma unroll
                for (int r = 0; r < 4; ++r)
                    Cq[(size_t)(row0 + r) * N + col] = acc[i][j][r];
            }
        }
    }
}

// ---------------------------------------------------------------------------
// xproj split-K reduce: dbc = sum_ks dbcp[ks]; dbch bf16 for dtproj A.
// ---------------------------------------------------------------------------
__global__ __launch_bounds__(256) void xproj_red_k(
    const float* __restrict__ dbcp, float* __restrict__ dbc,
    ushort_t* __restrict__ dbch)
{
    int g = blockIdx.x * 256 + threadIdx.x;      // over 4096*128
    int m = g >> 7, c = g & 127;
    float s = 0.f;
    #pragma unroll
    for (int ks = 0; ks < KSPL; ++ks)
        s += dbcp[(size_t)ks * M_TOT * DBC_STRIDE + g];
    dbc[g] = s;
    if (c < 64)
        dbch[(size_t)m * 64 + c] = f2bf_rne(s);
}

// ---------------------------------------------------------------------------
// out-proj split-K reduce: out = p0 + p1 (float4).
// ---------------------------------------------------------------------------
__global__ __launch_bounds__(256) void outred_k(
    const float* __restrict__ p, float* __restrict__ out)
{
    int i4 = (blockIdx.x * 256 + threadIdx.x) * 4;
    f32x4 a = *reinterpret_cast<const f32x4*>(p + i4);
    f32x4 b = *reinterpret_cast<const f32x4*>(p + (size_t)M_TOT * D_MODEL + i4);
    *reinterpret_cast<f32x4*>(out + i4) = a + b;
}

// ---------------------------------------------------------------------------
// x -> xh bf16 (hi only), elementwise.
// ---------------------------------------------------------------------------
__global__ __launch_bounds__(256) void cast_h_k(
    const float* __restrict__ X, ushort_t* __restrict__ Xh)
{
    int i4 = (blockIdx.x * 256 + threadIdx.x) * 4;
    float4 v = *reinterpret_cast<const float4*>(X + i4);
    ushort2 a = make_ushort2(f2bf_rne(v.x), f2bf_rne(v.y));
    ushort2 b = make_ushort2(f2bf_rne(v.z), f2bf_rne(v.w));
    *reinterpret_cast<ushort2*>(Xh + i4)     = a;
    *reinterpret_cast<ushort2*>(Xh + i4 + 2) = b;
}

// ---------------------------------------------------------------------------
// W[K][N] fp32 -> WT[N][K] bf16 hi/lo (tiled transpose, exact dims).
// ---------------------------------------------------------------------------
__global__ __launch_bounds__(256) void transpose_cast_k(
    const float* __restrict__ W, ushort_t* __restrict__ Th, ushort_t* __restrict__ Tl,
    int K, int N)
{
    __shared__ float tile[32][33];
    int n0 = blockIdx.x * 32, k0 = blockIdx.y * 32;
    int tx = threadIdx.x & 31, ty = threadIdx.x >> 5;
    #pragma unroll
    for (int i = 0; i < 32; i += 8)
        tile[ty + i][tx] = W[(size_t)(k0 + ty + i) * N + n0 + tx];
    __syncthreads();
    #pragma unroll
    for (int i = 0; i < 32; i += 8) {
        float v = tile[tx][ty + i];
        ushort_t h = f2bf_rne(v);
        ushort_t l = f2bf_rne(v - bf2f(h));
        size_t o = (size_t)(n0 + ty + i) * K + k0 + tx;
        Th[o] = h; Tl[o] = l;
    }
}

// ---------------------------------------------------------------------------
// W[K][N] fp32 -> WT[Npad][K] bf16 hi only, zero-padded rows N..Npad.
// ---------------------------------------------------------------------------
__global__ __launch_bounds__(256) void transpose_cast_pad_k(
    const float* __restrict__ W, ushort_t* __restrict__ Th, int K, int N)
{
    __shared__ float tile[32][33];
    int n0 = blockIdx.x * 32, k0 = blockIdx.y * 32;
    int tx = threadIdx.x & 31, ty = threadIdx.x >> 5;
    #pragma unroll
    for (int i = 0; i < 32; i += 8)
        tile[ty + i][tx] = (n0 + tx < N) ? W[(size_t)(k0 + ty + i) * N + n0 + tx] : 0.f;
    __syncthreads();
    #pragma unroll
    for (int i = 0; i < 32; i += 8) {
        float v = tile[tx][ty + i];
        size_t o = (size_t)(n0 + ty + i) * K + k0 + tx;
        Th[o] = f2bf_rne(v);
    }
}

// ---------------------------------------------------------------------------
// Depthwise causal conv + bias + SiLU. Reads compact xbuf[m][2048].
// Outputs xinh [m][d] bf16 (xproj A, 1-term) and xf [m][d] fp32 (scan).
// ---------------------------------------------------------------------------
__global__ __launch_bounds__(256) void conv_silu_k(
    const float* __restrict__ xbuf, const float* __restrict__ Wc,
    const float* __restrict__ bc, ushort_t* __restrict__ xinh,
    float* __restrict__ xf)
{
    __shared__ float tile[67][64];
    const int c0 = blockIdx.x * 64;
    const int m0 = blockIdx.y * 64;
    const int bstart = m0 & ~(LSEQ - 1);
    const int tid = threadIdx.x;

    for (int e = tid; e < 67 * 64; e += 256) {
        int r = e >> 6, c = e & 63;
        int g = m0 - 3 + r;
        tile[r][c] = (g >= bstart) ? xbuf[(size_t)g * D_INNER + c0 + c] : 0.f;
    }
    __syncthreads();

    const int c_l = tid & 63, mg = tid >> 6;
    const int c = c0 + c_l;
    const float w0 = Wc[c], w1 = Wc[D_INNER + c];
    const float w2 = Wc[2 * D_INNER + c], w3 = Wc[3 * D_INNER + c];
    const float bb = bc[c];
    #pragma unroll
    for (int mi = 0; mi < 16; ++mi) {
        int r = mg * 16 + mi;
        float acc = bb + tile[r][c_l] * w0 + tile[r + 1][c_l] * w1
                       + tile[r + 2][c_l] * w2 + tile[r + 3][c_l] * w3;
        float sv = acc / (1.f + __expf(-acc));
        xinh[(size_t)(m0 + r) * D_INNER + c] = f2bf_rne(sv);
        xf[(size_t)(m0 + r) * D_INNER + c] = sv;
    }
}

// ---------------------------------------------------------------------------
// Chunked selective scan, half-wave n-split version (512 thr = 8 waves).
// Lane l of wave w owns channel d = c0 + w*32 + (l&31) and 8 of the 16
// states (n0 = (l>>5)*8).  Twice the waves/CU and half the serial work per
// wave vs the 256-thr/16-state layout.  dt/x(/z) staged to LDS in 8-row
// groups, double-buffered, counted vmcnt (uniform per-wave call counts);
// B|C for the whole chunk staged once in the prologue.
// Pass 1: chunk summaries asum (log2 domain), s_end — no n-reduction needed.
// ---------------------------------------------------------------------------
__global__ __launch_bounds__(512) void scan_sum_k5(
    const float* __restrict__ dtf, const float* __restrict__ xf,
    const float* __restrict__ dbc, const float* __restrict__ A_log,
    float* __restrict__ asumb, float* __restrict__ sendb)
{
    __shared__ float sdt[2][8][256];
    __shared__ float sx[2][8][256];
    __shared__ float sBC[64][32];         // B|C whole chunk (8 KB; B used)
    const int tid = threadIdx.x;
    const int lane = tid & 63;
    const int w = tid >> 6;               // 0..7
    const int dloc = (w << 5) + (lane & 31);
    const int n0 = (lane >> 5) * 8;
    const int c0 = blockIdx.x << 8;
    const int ck = blockIdx.y;
    const int b  = blockIdx.z;
    const size_t mbase = (size_t)b * LSEQ + (size_t)ck * CH;
    const int d = c0 + dloc;

    // stage group G (8 rows x 256): wave w loads row w; 2 calls per wave
    auto stageG = [&](int G, int bf) {
        const size_t g = (mbase + G * 8 + w) * D_INNER + c0 + lane * 4;
        GLDS(dtf + g, &sdt[bf][w][0]);
        GLDS(xf + g,  &sx[bf][w][0]);
    };

    // prologue: BC chunk (1 call/wave: thread tid -> byte off tid*16)
    {
        const int row = tid >> 3, col = (tid & 7) * 4;
        GLDS(dbc + (mbase + row) * DBC_STRIDE + 64 + col, &sBC[w * 8][0]);
    }
    stageG(0, 0);
    stageG(1, 1);

    float AdnL2[8];
    #pragma unroll
    for (int j = 0; j < 8; ++j)
        AdnL2[j] = -__expf(A_log[d * D_STATE + n0 + j]) * LOG2E;

    float s[8] = {};
    float asum[8] = {};

    asm volatile("s_waitcnt vmcnt(2)" ::: "memory");   // BC + g0 resident
    BAR();

    for (int G = 0; G < 8; ++G) {
        const int bf = G & 1;
        #pragma unroll
        for (int t = 0; t < 8; ++t) {
            const int rr = G * 8 + t;
            const float dv = sdt[bf][t][dloc];
            const float xv = sx[bf][t][dloc];
            const float p  = dv * xv;
            #pragma unroll
            for (int j = 0; j < 8; ++j) {
                float a = fmaxf(dv * AdnL2[j], NLOG2E10);
                asum[j] += a;
                float e = fexp2(a);
                s[j] = clip10(fmaf(s[j], e, p * sBC[rr][n0 + j]));
            }
        }
        BAR();                                  // all waves done with buf bf
        if (G + 2 < 8) {
            stageG(G + 2, bf);                  // refill just-freed buffer
            asm volatile("s_waitcnt vmcnt(2)" ::: "memory");  // g+1 resident
        } else if (G == 6) {
            asm volatile("s_waitcnt vmcnt(0)" ::: "memory");  // g7 resident
        }
        BAR();
        __builtin_amdgcn_sched_barrier(0);
    }

    #pragma unroll
    for (int j = 0; j < 8; ++j) {
        size_t o = (((size_t)(b * NCH + ck) * 16) + n0 + j) * D_INNER + d;
        asumb[o] = asum[j];
        sendb[o] = s[j];
    }
}

// ---------------------------------------------------------------------------
// Pass 2: sequential combine over chunk summaries -> entry state per chunk.
// ---------------------------------------------------------------------------
__global__ __launch_bounds__(256) void scan_fix_k2(
    const float* __restrict__ asumb, const float* __restrict__ sendb,
    float* __restrict__ sinb)
{
    int g = blockIdx.x * 256 + threadIdx.x;     // d + 2048*(n + 16*b)
    int d = g & (D_INNER - 1);
    int n = (g >> 11) & 15;
    int b = g >> 15;
    float s = 0.f;
    for (int ck = 0; ck < NCH; ++ck) {
        size_t idx = (((size_t)(b * NCH + ck) * 16) + n) * D_INNER + d;
        sinb[idx] = s;
        s = clip10(fmaf(s, fexp2(asumb[idx]), sendb[idx]));
    }
}

// ---------------------------------------------------------------------------
// Pass 3: recompute local scan from entry state; each lane-half accumulates
// its 8 states' y-partial, cross-half reduce via __shfl_xor(32); half 0
// gates + stores y bf16 [m][d].
// ---------------------------------------------------------------------------
__global__ __launch_bounds__(512) void scan_apply_k5(
    const float* __restrict__ dtf, const float* __restrict__ xf,
    const float* __restrict__ dbc, const float* __restrict__ zf,
    const float* __restrict__ sinb, const float* __restrict__ A_log,
    const float* __restrict__ Dv, ushort_t* __restrict__ Yh)
{
    __shared__ float sdt[2][8][256];
    __shared__ float sx[2][8][256];
    __shared__ float sz[2][8][256];
    __shared__ float sBC[64][32];         // B|C whole chunk (8 KB)
    const int tid = threadIdx.x;
    const int lane = tid & 63;
    const int w = tid >> 6;
    const int dloc = (w << 5) + (lane & 31);
    const int n0 = (lane >> 5) * 8;
    const int c0 = blockIdx.x << 8;
    const int ck = blockIdx.y;
    const int b  = blockIdx.z;
    const size_t mbase = (size_t)b * LSEQ + (size_t)ck * CH;
    const int d = c0 + dloc;

    // stage group G: wave w loads row w of dt/x/z; 3 calls per wave
    auto stageG = [&](int G, int bf) {
        const size_t g = (mbase + G * 8 + w) * D_INNER + c0 + lane * 4;
        GLDS(dtf + g, &sdt[bf][w][0]);
        GLDS(xf + g,  &sx[bf][w][0]);
        GLDS(zf + g,  &sz[bf][w][0]);
    };

    // prologue: BC chunk (1 call/wave) + g0 (3) + g1 (3) = 7 outstanding
    {
        const int row = tid >> 3, col = (tid & 7) * 4;
        GLDS(dbc + (mbase + row) * DBC_STRIDE + 64 + col, &sBC[w * 8][0]);
    }
    stageG(0, 0);
    stageG(1, 1);

    float AdnL2[8];
    #pragma unroll
    for (int j = 0; j < 8; ++j)
        AdnL2[j] = -__expf(A_log[d * D_STATE + n0 + j]) * LOG2E;
    const float Dd = Dv[d];

    float s[8];
    #pragma unroll
    for (int j = 0; j < 8; ++j)
        s[j] = sinb[(((size_t)(b * NCH + ck) * 16) + n0 + j) * D_INNER + d];

    asm volatile("s_waitcnt vmcnt(3)" ::: "memory");   // BC + g0 resident
    BAR();

    for (int G = 0; G < 8; ++G) {
        const int bf = G & 1;
        #pragma unroll
        for (int t = 0; t < 8; ++t) {
            const int rr = G * 8 + t;
            const float dv = sdt[bf][t][dloc];
            const float xv = sx[bf][t][dloc];
            const float p  = dv * xv;
            float y0 = 0.f, y1 = 0.f;
            #pragma unroll
            for (int j = 0; j < 8; j += 2) {
                float a0 = fmaxf(dv * AdnL2[j + 0], NLOG2E10);
                float a1 = fmaxf(dv * AdnL2[j + 1], NLOG2E10);
                s[j + 0] = clip10(fmaf(s[j + 0], fexp2(a0), p * sBC[rr][n0 + j + 0]));
                s[j + 1] = clip10(fmaf(s[j + 1], fexp2(a1), p * sBC[rr][n0 + j + 1]));
                y0 = fmaf(s[j + 0], sBC[rr][16 + n0 + j + 0], y0);
                y1 = fmaf(s[j + 1], sBC[rr][16 + n0 + j + 1], y1);
            }
            float y = y0 + y1;
            y += __shfl_xor(y, 32, 64);        // combine the two n-halves
            if (lane < 32) {
                const float yf = y + Dd * xv;
                const float zz = sz[bf][t][dloc];
                const float gate = zz * frcp(1.f + fexp2(zz * -LOG2E));
                Yh[(mbase + rr) * D_INNER + d] = f2bf_rne(yf * gate);
            }
        }
        BAR();
        if (G + 2 < 8) {
            stageG(G + 2, bf);
            asm volatile("s_waitcnt vmcnt(3)" ::: "memory");
        } else if (G == 6) {
            asm volatile("s_waitcnt vmcnt(0)" ::: "memory");
        }
        BAR();
        __builtin_amdgcn_sched_barrier(0);
    }
}

// ---------------------------------------------------------------------------
extern "C" void kernel_launch(void* const* d_in, const int* in_sizes, int n_in,
                              void* d_out, int out_size, void* d_ws, size_t ws_size,
                              hipStream_t stream)
{
    const float* x       = (const float*)d_in[0];
    const float* W_in    = (const float*)d_in[1];
    const float* W_conv  = (const float*)d_in[2];
    const float* b_conv  = (const float*)d_in[3];
    const float* W_xproj = (const float*)d_in[4];
    const float* W_dt    = (const float*)d_in[5];
    const float* b_dt    = (const float*)d_in[6];
    const float* A_log   = (const float*)d_in[7];
    const float* Dv      = (const float*)d_in[8];
    const float* W_out   = (const float*)d_in[9];
    float* out = (float*)d_out;

    // fp32 region
    float* xbuf = (float*)d_ws;                              // [4096][2048]
    float* zf   = xbuf + (size_t)M_TOT * D_INNER;            // [4096][2048] z row-major
    float* dbc  = zf + (size_t)M_TOT * D_INNER;              // [4096][128]
    float* BCT  = dbc + (size_t)M_TOT * DBC_STRIDE;          // (unused slot)
    // bf16 region (layout slots; several aliased below)
    ushort_t* xh     = (ushort_t*)(BCT + (size_t)32 * M_TOT);
    ushort_t* xl     = xh + (size_t)M_TOT * D_MODEL;          // (slot)
    ushort_t* WinTh  = xl + (size_t)M_TOT * D_MODEL;          // [4096][1024]
    ushort_t* WinTl  = WinTh + (size_t)2 * D_INNER * D_MODEL; // (slot)
    ushort_t* WoutTh = WinTl + (size_t)2 * D_INNER * D_MODEL; // [1024][2048]
    ushort_t* WoutTl = WoutTh + (size_t)D_MODEL * D_INNER;
    ushort_t* WxTh   = WoutTl + (size_t)D_MODEL * D_INNER;    // [128][2048]
    ushort_t* WxTl   = WxTh + (size_t)DBC_STRIDE * D_INNER;   // (slot)
    ushort_t* xinh   = WxTl + (size_t)DBC_STRIDE * D_INNER;   // [4096][2048]
    ushort_t* xinl   = xinh + (size_t)M_TOT * D_INNER;        // (slot)
    ushort_t* yh     = xinl + (size_t)M_TOT * D_INNER;        // [4096][2048]
    ushort_t* yl     = yh + (size_t)M_TOT * D_INNER;          // (slot)
    ushort_t* WdtTh  = yl + (size_t)M_TOT * D_INNER;          // [2048][64]
    ushort_t* dbch   = WdtTh + (size_t)D_INNER * DT_RANK;     // [4096][64]
    // aliases (stream-ordered reuse of dead regions):
    float* xf   = (float*)xh;    // [4096][2048] over xh|xl|WinTh|WinTl (dead after gemm#1)
    float* dtf  = (float*)xinh;  // [4096][2048] over xinh|xinl (dead after xproj gemm)
    float* dbcp = (float*)yh;    // [8][4096][128] over yh|yl (dead until scan_apply)
    float* pout = (float*)xh;    // [2][4096][1024] over xf region (dead after scan)
    const size_t NSUM = (size_t)NBATCH * NCH * D_INNER * D_STATE;
    float* asumb = xbuf;         // over xbuf (dead after conv)
    float* sendb = xbuf + NSUM;
    float* sinb  = xbuf + 2 * NSUM;

    // precompute: casts + weight transposes
    cast_h_k<<<(M_TOT * D_MODEL) / 1024, 256, 0, stream>>>(x, xh);
    transpose_cast_pad_k<<<dim3((2 * D_INNER) / 32, D_MODEL / 32), 256, 0, stream>>>(
        W_in, WinTh, D_MODEL, 2 * D_INNER);
    transpose_cast_k<<<dim3(D_MODEL / 32, D_INNER / 32), 256, 0, stream>>>(
        W_out, WoutTh, WoutTl, D_INNER, D_MODEL);
    transpose_cast_pad_k<<<dim3(DBC_STRIDE / 32, D_INNER / 32), 256, 0, stream>>>(
        W_xproj, WxTh, D_INNER, DT_RANK + 2 * D_STATE);
    transpose_cast_pad_k<<<dim3(D_INNER / 32, DT_RANK / 32), 256, 0, stream>>>(
        W_dt, WdtTh, DT_RANK, D_INNER);

    // 1) in-proj (256x256 8-phase): x-half -> xbuf, z-half -> zf[m][d]
    gemm256_inproj<<<dim3(16, 16), 512, 0, stream>>>(xh, WinTh, xbuf, zf);
    // 2) conv + silu -> xinh [m][d] bf16 + xf [m][d] fp32
    conv_silu_k<<<dim3(D_INNER / 64, M_TOT / 64), 256, 0, stream>>>(
        xbuf, W_conv, b_conv, xinh, xf);
    // 3) xproj (1-term, K-split x8) -> dbcp partials -> dbc + dbch bf16
    gemm_bf16s<3, 1><<<dim3(KSPL, 32), 256, 0, stream>>>(
        xinh, nullptr, WxTh, nullptr, dbcp, nullptr, M_TOT, DBC_STRIDE, D_INNER);
    xproj_red_k<<<(M_TOT * DBC_STRIDE) / 256, 256, 0, stream>>>(dbcp, dbc, dbch);
    // 4) dtproj via MFMA (MODE 5): dtf[m][d] = softplus(dbch @ WdtT + b_dt)
    gemm_bf16s<5, 1><<<dim3(D_INNER / 128, M_TOT / 128), 256, 0, stream>>>(
        dbch, nullptr, WdtTh, nullptr, dtf, (float*)b_dt, M_TOT, D_INNER, DT_RANK);
    // 5) chunked scan (half-wave n-split): sum -> fix -> apply+gate
    scan_sum_k5<<<dim3(D_INNER / 256, NCH, NBATCH), 512, 0, stream>>>(
        dtf, xf, dbc, A_log, asumb, sendb);
    scan_fix_k2<<<(NBATCH * D_STATE * D_INNER) / 256, 256, 0, stream>>>(
        asumb, sendb, sinb);
    scan_apply_k5<<<dim3(D_INNER / 256, NCH, NBATCH), 512, 0, stream>>>(
        dtf, xf, dbc, zf, sinb, A_log, Dv, yh);
    // 6) out-proj (256x128 8-phase 2-term, K-split x2) -> pout partials -> out
    gemm256_outproj<<<dim3(16, 16), 512, 0, stream>>>(yh, WoutTh, WoutTl, pout);
    outred_k<<<(M_TOT * D_MODEL) / 1024, 256, 0, stream>>>(pout, out);
}